// Round 2
// baseline (2795.582 us; speedup 1.0000x reference)
//
#include <hip/hip_runtime.h>
#include <math.h>

#define N_NODES 50000
#define N_EDGES 800000
#define DIM 64
#define NB 256
#define NK 4
#define NC 10

__device__ __forceinline__ float sigmoidf_(float x){ return 1.f/(1.f+__expf(-x)); }

// ---------------- CSR build ----------------
__global__ void deg_hist_kernel(const int* __restrict__ ei, int* __restrict__ deg){
    int e = blockIdx.x*256 + threadIdx.x;
    if (e < N_EDGES) atomicAdd(&deg[ei[N_EDGES + e]], 1);
}

__global__ __launch_bounds__(1024)
void scan_kernel(const int* __restrict__ deg, int* __restrict__ rowptr, int* __restrict__ cursor){
    __shared__ int s[1024];
    __shared__ int base;
    int tid = threadIdx.x;
    if (tid == 0) base = 0;
    __syncthreads();
    for (int c = 0; c < N_NODES; c += 1024){
        int v = (c + tid < N_NODES) ? deg[c + tid] : 0;
        s[tid] = v;
        __syncthreads();
        for (int off = 1; off < 1024; off <<= 1){
            int t = (tid >= off) ? s[tid - off] : 0;
            __syncthreads();
            s[tid] += t;
            __syncthreads();
        }
        int excl = base + s[tid] - v;
        if (c + tid < N_NODES){ rowptr[c + tid] = excl; cursor[c + tid] = excl; }
        __syncthreads();
        if (tid == 0) base += s[1023];
        __syncthreads();
    }
    if (tid == 0) rowptr[N_NODES] = base;
}

__global__ void csr_fill_kernel(const int* __restrict__ ei, int* __restrict__ cursor,
                                int* __restrict__ csr_src, int* __restrict__ csr_eid){
    int e = blockIdx.x*256 + threadIdx.x;
    if (e < N_EDGES){
        int d = ei[N_EDGES + e];
        int pos = atomicAdd(&cursor[d], 1);
        csr_src[pos] = ei[e];
        csr_eid[pos] = e;
    }
}

// ---------------- gather edge weights into CSR order (per expert) ----------------
__global__ void gather_ew_kernel(const int* __restrict__ csr_eid, const float* __restrict__ em_out,
                                 float* __restrict__ ew_csr, int k){
    int i = blockIdx.x*256 + threadIdx.x;
    if (i < N_EDGES) ew_csr[i] = em_out[csr_eid[i]*NK + k];
}

// ---------------- fused GIN layer: aggregate + 2-layer MLP ----------------
template<bool HAS_EW>
__global__ __launch_bounds__(256)
void gin_layer(const float* __restrict__ hin, float* __restrict__ hout,
               const int* __restrict__ rowptr, const int* __restrict__ csr_src,
               const float* __restrict__ ew_csr, // CSR-ordered weights (HAS_EW only)
               const float* __restrict__ W1, const float* __restrict__ b1,
               const float* __restrict__ W2, const float* __restrict__ b2,
               const float* __restrict__ eps_p)
{
    __shared__ __align__(16) float ts[4][DIM];
    const int wave = threadIdx.x >> 6;
    const int lane = threadIdx.x & 63;
    float w1r[DIM], w2r[DIM];
#pragma unroll
    for (int i = 0; i < DIM; i++) w1r[i] = W1[i*DIM + lane];
#pragma unroll
    for (int i = 0; i < DIM; i++) w2r[i] = W2[i*DIM + lane];
    const float bb1 = b1[lane], bb2 = b2[lane];
    const float epv = 1.0f + *eps_p;
    const int stride = gridDim.x * 4;
    for (int n = blockIdx.x*4 + wave; n < N_NODES; n += stride){
        float acc = epv * hin[n*DIM + lane];
        int idx = rowptr[n];
        const int end = rowptr[n+1];
        for (; idx + 4 <= end; idx += 4){
            int s0 = csr_src[idx+0], s1 = csr_src[idx+1], s2 = csr_src[idx+2], s3 = csr_src[idx+3];
            float g0 = hin[s0*DIM + lane], g1 = hin[s1*DIM + lane];
            float g2 = hin[s2*DIM + lane], g3 = hin[s3*DIM + lane];
            if (HAS_EW){
                acc += ew_csr[idx+0]*g0 + ew_csr[idx+1]*g1 + ew_csr[idx+2]*g2 + ew_csr[idx+3]*g3;
            } else {
                acc += g0 + g1 + g2 + g3;
            }
        }
        for (; idx < end; ++idx){
            int s = csr_src[idx];
            float g = hin[s*DIM + lane];
            if (HAS_EW) g *= ew_csr[idx];
            acc += g;
        }
        ts[wave][lane] = acc;
        float u = bb1;
#pragma unroll
        for (int i = 0; i < 16; i++){
            float4 t = *(const float4*)&ts[wave][4*i];
            u = fmaf(t.x, w1r[4*i+0], u); u = fmaf(t.y, w1r[4*i+1], u);
            u = fmaf(t.z, w1r[4*i+2], u); u = fmaf(t.w, w1r[4*i+3], u);
        }
        u = fmaxf(u, 0.f);
        ts[wave][lane] = u;
        float v = bb2;
#pragma unroll
        for (int i = 0; i < 16; i++){
            float4 t = *(const float4*)&ts[wave][4*i];
            v = fmaf(t.x, w2r[4*i+0], v); v = fmaf(t.y, w2r[4*i+1], v);
            v = fmaf(t.z, w2r[4*i+2], v); v = fmaf(t.w, w2r[4*i+3], v);
        }
        hout[n*DIM + lane] = fmaxf(v, 0.f);
    }
}

// ---------------- node-mask + feat-mask MLPs (per expert k = blockIdx.y) ----------------
__global__ __launch_bounds__(256)
void mask_nf_kernel(const float* __restrict__ Z,
                    const float* __restrict__ nmW1, const float* __restrict__ nmb1,
                    const float* __restrict__ nmW2, const float* __restrict__ nmb2,
                    const float* __restrict__ fmW1, const float* __restrict__ fmb1,
                    const float* __restrict__ fmW2, const float* __restrict__ fmb2,
                    float* __restrict__ nm_out, float* __restrict__ fm_out)
{
    const int k = blockIdx.y;
    __shared__ float sW0[DIM*DIM], sW1[DIM*DIM], sW2[DIM*DIM];
    __shared__ float sb0[DIM], sb1[DIM], sb2[DIM], sw2n[DIM];
    __shared__ __align__(16) float ts[4][DIM];
    for (int i = threadIdx.x; i < DIM*DIM; i += 256){
        sW0[i] = nmW1[k*DIM*DIM + i];
        sW1[i] = fmW1[k*DIM*DIM + i];
        sW2[i] = fmW2[k*DIM*DIM + i];
    }
    if (threadIdx.x < DIM){
        sb0[threadIdx.x]  = nmb1[k*DIM + threadIdx.x];
        sb1[threadIdx.x]  = fmb1[k*DIM + threadIdx.x];
        sb2[threadIdx.x]  = fmb2[k*DIM + threadIdx.x];
        sw2n[threadIdx.x] = nmW2[k*DIM + threadIdx.x];
    }
    __syncthreads();
    const float nmb2v = nmb2[k];
    const int wave = threadIdx.x >> 6;
    const int lane = threadIdx.x & 63;
    const int stride = gridDim.x * 4;
    for (int n = blockIdx.x*4 + wave; n < N_NODES; n += stride){
        float z = Z[n*DIM + lane];
        ts[wave][lane] = z;
        float u = sb0[lane], h = sb1[lane];
#pragma unroll
        for (int i = 0; i < 16; i++){
            float4 t = *(const float4*)&ts[wave][4*i];
            u = fmaf(t.x, sW0[(4*i+0)*DIM + lane], u);
            u = fmaf(t.y, sW0[(4*i+1)*DIM + lane], u);
            u = fmaf(t.z, sW0[(4*i+2)*DIM + lane], u);
            u = fmaf(t.w, sW0[(4*i+3)*DIM + lane], u);
            h = fmaf(t.x, sW1[(4*i+0)*DIM + lane], h);
            h = fmaf(t.y, sW1[(4*i+1)*DIM + lane], h);
            h = fmaf(t.z, sW1[(4*i+2)*DIM + lane], h);
            h = fmaf(t.w, sW1[(4*i+3)*DIM + lane], h);
        }
        u = fmaxf(u, 0.f);
        h = fmaxf(h, 0.f);
        // node mask: dot(u, nmW2) + b2 -> sigmoid
        float p = u * sw2n[lane];
#pragma unroll
        for (int off = 1; off < 64; off <<= 1) p += __shfl_xor(p, off);
        if (lane == 0) nm_out[n*NK + k] = sigmoidf_(p + nmb2v);
        // feat mask layer 2
        ts[wave][lane] = h;
        float f = sb2[lane];
#pragma unroll
        for (int i = 0; i < 16; i++){
            float4 t = *(const float4*)&ts[wave][4*i];
            f = fmaf(t.x, sW2[(4*i+0)*DIM + lane], f);
            f = fmaf(t.y, sW2[(4*i+1)*DIM + lane], f);
            f = fmaf(t.z, sW2[(4*i+2)*DIM + lane], f);
            f = fmaf(t.w, sW2[(4*i+3)*DIM + lane], f);
        }
        fm_out[(n*NK + k)*DIM + lane] = sigmoidf_(f);
    }
}

// ---------------- edge-mask projections: Ptop = Z @ W1[0:64], Pbot = Z @ W1[64:128] ----------------
__global__ __launch_bounds__(256)
void em_proj_kernel(const float* __restrict__ Z, const float* __restrict__ W1 /* k-offset, [128,64] */,
                    float* __restrict__ pt, float* __restrict__ pb)
{
    __shared__ __align__(16) float ts[4][DIM];
    const int wave = threadIdx.x >> 6;
    const int lane = threadIdx.x & 63;
    float wt[DIM], wb[DIM];
#pragma unroll
    for (int i = 0; i < DIM; i++) wt[i] = W1[i*DIM + lane];
#pragma unroll
    for (int i = 0; i < DIM; i++) wb[i] = W1[(DIM + i)*DIM + lane];
    const int stride = gridDim.x * 4;
    for (int n = blockIdx.x*4 + wave; n < N_NODES; n += stride){
        ts[wave][lane] = Z[n*DIM + lane];
        float a = 0.f, b = 0.f;
#pragma unroll
        for (int i = 0; i < 16; i++){
            float4 t = *(const float4*)&ts[wave][4*i];
            a = fmaf(t.x, wt[4*i+0], a); a = fmaf(t.y, wt[4*i+1], a);
            a = fmaf(t.z, wt[4*i+2], a); a = fmaf(t.w, wt[4*i+3], a);
            b = fmaf(t.x, wb[4*i+0], b); b = fmaf(t.y, wb[4*i+1], b);
            b = fmaf(t.z, wb[4*i+2], b); b = fmaf(t.w, wb[4*i+3], b);
        }
        pt[n*DIM + lane] = a;
        pb[n*DIM + lane] = b;
    }
}

// ---------------- edge mask: 16 lanes per edge ----------------
__global__ __launch_bounds__(256)
void edge_mask_kernel(const int* __restrict__ ei, const float* __restrict__ pt, const float* __restrict__ pb,
                      const float* __restrict__ b1 /*k-offset*/, const float* __restrict__ w2 /*k-offset*/,
                      const float* __restrict__ b2p /*k-offset*/, float* __restrict__ em_out, int k)
{
    const int sub = threadIdx.x & 15;
    const float4 w2v = *(const float4*)&w2[sub*4];
    const float4 b1v = *(const float4*)&b1[sub*4];
    const float b2 = *b2p;
    const int estart = blockIdx.x*16 + (threadIdx.x >> 4);
    const int estride = gridDim.x * 16;
    for (int e = estart; e < N_EDGES; e += estride){
        int s = ei[e], d = ei[N_EDGES + e];
        float4 a  = *(const float4*)&pt[s*DIM + sub*4];
        float4 bb = *(const float4*)&pb[d*DIM + sub*4];
        float h0 = fmaxf(a.x + bb.x + b1v.x, 0.f);
        float h1 = fmaxf(a.y + bb.y + b1v.y, 0.f);
        float h2 = fmaxf(a.z + bb.z + b1v.z, 0.f);
        float h3 = fmaxf(a.w + bb.w + b1v.w, 0.f);
        float p = h0*w2v.x + h1*w2v.y + h2*w2v.z + h3*w2v.w;
        p += __shfl_xor(p, 1, 16);
        p += __shfl_xor(p, 2, 16);
        p += __shfl_xor(p, 4, 16);
        p += __shfl_xor(p, 8, 16);
        if (sub == 0) em_out[e*NK + k] = sigmoidf_(p + b2);
    }
}

// ---------------- masked_x for expert k ----------------
__global__ void build_h0_kernel(const float* __restrict__ x, const float* __restrict__ nm_out,
                                const float* __restrict__ fm_out, float* __restrict__ h0, int k)
{
    int t = blockIdx.x*256 + threadIdx.x;
    if (t < N_NODES*DIM){
        int n = t >> 6, j = t & 63;
        h0[t] = x[t] * nm_out[n*NK + k] * fm_out[(n*NK + k)*DIM + j];
    }
}

// ---------------- pooling (batch is sorted -> binary search segment) ----------------
__device__ __forceinline__ int lower_bound_(const int* a, int n, int v){
    int lo = 0, hi = n;
    while (lo < hi){ int m = (lo + hi) >> 1; if (a[m] < v) lo = m + 1; else hi = m; }
    return lo;
}

__global__ __launch_bounds__(64)
void pool_orig_kernel(const float* __restrict__ h, const int* __restrict__ batch, float* __restrict__ out){
    int b = blockIdx.x, lane = threadIdx.x;
    int lo = lower_bound_(batch, N_NODES, b);
    int hi = lower_bound_(batch, N_NODES, b+1);
    float s = 0.f;
    for (int n = lo; n < hi; ++n) s += h[n*DIM + lane];
    out[b*DIM + lane] = s / fmaxf((float)(hi - lo), 1.f);
}

__global__ __launch_bounds__(64)
void pool_expert_kernel(const float* __restrict__ h, const int* __restrict__ batch,
                        const float* __restrict__ clfW /*k-offset [64,10]*/, const float* __restrict__ clfb /*k-offset*/,
                        float* __restrict__ out_logits, float* __restrict__ out_hst, int k)
{
    __shared__ float ms[DIM];
    int b = blockIdx.x, lane = threadIdx.x;
    int lo = lower_bound_(batch, N_NODES, b);
    int hi = lower_bound_(batch, N_NODES, b+1);
    float s = 0.f;
    for (int n = lo; n < hi; ++n) s += h[n*DIM + lane];
    float m = s / fmaxf((float)(hi - lo), 1.f);
    out_hst[(b*NK + k)*DIM + lane] = m;
    ms[lane] = m;
    __syncthreads();
    if (lane < NC){
        float a = clfb[lane];
#pragma unroll
        for (int j = 0; j < DIM; j++) a = fmaf(ms[j], clfW[j*NC + lane], a);
        out_logits[(b*NK + k)*NC + lane] = a;
    }
}

// ---------------- launch ----------------
extern "C" void kernel_launch(void* const* d_in, const int* in_sizes, int n_in,
                              void* d_out, int out_size, void* d_ws, size_t ws_size,
                              hipStream_t stream)
{
    const float* x     = (const float*)d_in[0];
    const int*   ei    = (const int*)  d_in[1];
    const int*   batch = (const int*)  d_in[2];
    const float* ceW1 = (const float*)d_in[3];
    const float* ceb1 = (const float*)d_in[4];
    const float* ceW2 = (const float*)d_in[5];
    const float* ceb2 = (const float*)d_in[6];
    const float* ceeps= (const float*)d_in[7];
    const float* clW1 = (const float*)d_in[8];
    const float* clb1 = (const float*)d_in[9];
    const float* clW2 = (const float*)d_in[10];
    const float* clb2 = (const float*)d_in[11];
    const float* cleps= (const float*)d_in[12];
    const float* nmW1 = (const float*)d_in[13];
    const float* nmb1 = (const float*)d_in[14];
    const float* nmW2 = (const float*)d_in[15];
    const float* nmb2 = (const float*)d_in[16];
    const float* emW1 = (const float*)d_in[17];
    const float* emb1 = (const float*)d_in[18];
    const float* emW2 = (const float*)d_in[19];
    const float* emb2 = (const float*)d_in[20];
    const float* fmW1 = (const float*)d_in[21];
    const float* fmb1 = (const float*)d_in[22];
    const float* fmW2 = (const float*)d_in[23];
    const float* fmb2 = (const float*)d_in[24];
    const float* clfW = (const float*)d_in[25];
    const float* clfb = (const float*)d_in[26];

    // output layout (f32, flat, return order)
    float* out        = (float*)d_out;
    float* out_logits = out;                       // [B,K,C]     10240
    float* out_hst    = out + 10240;               // [B,K,H]     65536
    float* out_horig  = out + 75776;               // [B,H]       16384
    float* nm_out     = out + 92160;               // [N,K]       200000
    float* em_out     = out + 292160;              // [E,K]       3200000
    float* fm_out     = out + 3492160;             // [N,K,F]     12800000

    // workspace layout
    int* rowptr  = (int*)d_ws;                     // N+1
    int* cursor  = rowptr + (N_NODES + 1);         // N
    int* deg     = cursor + N_NODES;               // N
    int* csr_src = deg + N_NODES;                  // E
    int* csr_eid = csr_src + N_EDGES;              // E
    size_t int_count = (size_t)(N_NODES+1) + N_NODES + N_NODES + N_EDGES + N_EDGES;
    int_count = (int_count + 3) & ~(size_t)3;
    float* hA = (float*)(((int*)d_ws) + int_count);   // N*64   (Z lives here after CE)
    float* hB = hA + (size_t)N_NODES*DIM;             // N*64
    float* C1 = hB + (size_t)N_NODES*DIM;             // N*64
    float* C2 = C1 + (size_t)N_NODES*DIM;             // N*64
    float* ew_csr = C2 + (size_t)N_NODES*DIM;         // E

    // ---- CSR build ----
    hipMemsetAsync(deg, 0, N_NODES*sizeof(int), stream);
    deg_hist_kernel<<<(N_EDGES+255)/256, 256, 0, stream>>>(ei, deg);
    scan_kernel<<<1, 1024, 0, stream>>>(deg, rowptr, cursor);
    csr_fill_kernel<<<(N_EDGES+255)/256, 256, 0, stream>>>(ei, cursor, csr_src, csr_eid);

    // ---- causal encoder GIN (3 layers): x -> hA -> hB -> hA ----
    gin_layer<false><<<1024, 256, 0, stream>>>(x,  hA, rowptr, csr_src, nullptr,
        ceW1 + 0*DIM*DIM, ceb1 + 0*DIM, ceW2 + 0*DIM*DIM, ceb2 + 0*DIM, ceeps + 0);
    gin_layer<false><<<1024, 256, 0, stream>>>(hA, hB, rowptr, csr_src, nullptr,
        ceW1 + 1*DIM*DIM, ceb1 + 1*DIM, ceW2 + 1*DIM*DIM, ceb2 + 1*DIM, ceeps + 1);
    gin_layer<false><<<1024, 256, 0, stream>>>(hB, hA, rowptr, csr_src, nullptr,
        ceW1 + 2*DIM*DIM, ceb1 + 2*DIM, ceW2 + 2*DIM*DIM, ceb2 + 2*DIM, ceeps + 2);
    const float* Z = hA;

    // ---- h_orig pooling ----
    pool_orig_kernel<<<NB, 64, 0, stream>>>(Z, batch, out_horig);

    // ---- node & feature masks ----
    mask_nf_kernel<<<dim3(256, NK), 256, 0, stream>>>(Z, nmW1, nmb1, nmW2, nmb2,
                                                      fmW1, fmb1, fmW2, fmb2, nm_out, fm_out);

    // ---- per-expert: edge masks + classifier GIN + pooling ----
    for (int k = 0; k < NK; ++k){
        em_proj_kernel<<<1024, 256, 0, stream>>>(Z, emW1 + k*2*DIM*DIM, hB, C1);
        edge_mask_kernel<<<4096, 256, 0, stream>>>(ei, hB, C1, emb1 + k*DIM, emW2 + k*DIM,
                                                   emb2 + k, em_out, k);
        gather_ew_kernel<<<(N_EDGES+255)/256, 256, 0, stream>>>(csr_eid, em_out, ew_csr, k);
        build_h0_kernel<<<(N_NODES*DIM+255)/256, 256, 0, stream>>>(x, nm_out, fm_out, C2, k);
        gin_layer<true><<<1024, 256, 0, stream>>>(C2, hB, rowptr, csr_src, ew_csr,
            clW1 + 0*DIM*DIM, clb1 + 0*DIM, clW2 + 0*DIM*DIM, clb2 + 0*DIM, cleps + 0);
        gin_layer<true><<<1024, 256, 0, stream>>>(hB, C1, rowptr, csr_src, ew_csr,
            clW1 + 1*DIM*DIM, clb1 + 1*DIM, clW2 + 1*DIM*DIM, clb2 + 1*DIM, cleps + 1);
        gin_layer<true><<<1024, 256, 0, stream>>>(C1, C2, rowptr, csr_src, ew_csr,
            clW1 + 2*DIM*DIM, clb1 + 2*DIM, clW2 + 2*DIM*DIM, clb2 + 2*DIM, cleps + 2);
        pool_expert_kernel<<<NB, 64, 0, stream>>>(C2, batch, clfW + k*DIM*NC, clfb + k*NC,
                                                  out_logits, out_hst, k);
    }
}

// Round 3
// 1811.813 us; speedup vs baseline: 1.5430x; 1.5430x over previous
//
#include <hip/hip_runtime.h>
#include <math.h>

#define N_NODES 50000
#define N_EDGES 800000
#define DIM 64
#define NB 256
#define NK 4
#define NC 10
#define TPAD 68
#define SCAN_BLKS 196  // ceil(50000/256)

__device__ __forceinline__ float sigmoidf_(float x){ return 1.f/(1.f+__expf(-x)); }

// ---------------- CSR build ----------------
__global__ void deg_hist_kernel(const int* __restrict__ ei, int* __restrict__ deg){
    int e = blockIdx.x*256 + threadIdx.x;
    if (e < N_EDGES) atomicAdd(&deg[ei[N_EDGES + e]], 1);
}

__global__ __launch_bounds__(256)
void scan_p1(const int* __restrict__ deg, int* __restrict__ rowptr, int* __restrict__ bsum){
    __shared__ int s[256];
    int tid = threadIdx.x;
    int i = blockIdx.x*256 + tid;
    int v = (i < N_NODES) ? deg[i] : 0;
    s[tid] = v;
    __syncthreads();
    for (int off = 1; off < 256; off <<= 1){
        int t = (tid >= off) ? s[tid - off] : 0;
        __syncthreads();
        s[tid] += t;
        __syncthreads();
    }
    if (i < N_NODES) rowptr[i] = s[tid] - v;   // block-local exclusive
    if (tid == 255) bsum[blockIdx.x] = s[255];
}

__global__ __launch_bounds__(256)
void scan_p2(const int* __restrict__ bsum, int* __restrict__ boff){
    __shared__ int s[256];
    int tid = threadIdx.x;
    int v = (tid < SCAN_BLKS) ? bsum[tid] : 0;
    s[tid] = v;
    __syncthreads();
    for (int off = 1; off < 256; off <<= 1){
        int t = (tid >= off) ? s[tid - off] : 0;
        __syncthreads();
        s[tid] += t;
        __syncthreads();
    }
    boff[tid] = s[tid] - v;   // exclusive
}

__global__ __launch_bounds__(256)
void scan_p3(int* __restrict__ rowptr, const int* __restrict__ boff, int* __restrict__ cursor){
    int i = blockIdx.x*256 + threadIdx.x;
    if (i < N_NODES){
        int r = rowptr[i] + boff[blockIdx.x];
        rowptr[i] = r;
        cursor[i] = r;
    }
    if (i == 0) rowptr[N_NODES] = N_EDGES;
}

__global__ void csr_fill_kernel(const int* __restrict__ ei, int* __restrict__ cursor,
                                int* __restrict__ csr_src, int* __restrict__ csr_eid){
    int e = blockIdx.x*256 + threadIdx.x;
    if (e < N_EDGES){
        int d = ei[N_EDGES + e];
        int pos = atomicAdd(&cursor[d], 1);
        csr_src[pos] = ei[e];
        csr_eid[pos] = e;
    }
}

// ---------------- gather edge weights into CSR order (per expert) ----------------
__global__ void gather_ew_kernel(const int* __restrict__ csr_eid, const float* __restrict__ em_out,
                                 float* __restrict__ ew_csr, int k){
    int i = blockIdx.x*256 + threadIdx.x;
    if (i < N_EDGES) ew_csr[i] = em_out[csr_eid[i]*NK + k];
}

// ---------------- aggregation: t = (1+eps)*h + sum_j [ew_j] h_j  (wave per node) ----------------
template<bool HAS_EW>
__global__ __launch_bounds__(256)
void agg_kernel(const float* __restrict__ hin, float* __restrict__ outt,
                const int* __restrict__ rowptr, const int* __restrict__ csr_src,
                const float* __restrict__ ew_csr, const float* __restrict__ eps_p)
{
    const int n = blockIdx.x*4 + (threadIdx.x >> 6);
    if (n >= N_NODES) return;
    const int lane = threadIdx.x & 63;
    const float epv = 1.0f + *eps_p;
    float acc = epv * hin[(size_t)n*DIM + lane];
    int idx = rowptr[n];
    const int end = rowptr[n+1];
    for (; idx + 4 <= end; idx += 4){
        int s0 = csr_src[idx+0], s1 = csr_src[idx+1], s2 = csr_src[idx+2], s3 = csr_src[idx+3];
        float g0 = hin[(size_t)s0*DIM + lane], g1 = hin[(size_t)s1*DIM + lane];
        float g2 = hin[(size_t)s2*DIM + lane], g3 = hin[(size_t)s3*DIM + lane];
        if (HAS_EW){
            acc += ew_csr[idx+0]*g0 + ew_csr[idx+1]*g1 + ew_csr[idx+2]*g2 + ew_csr[idx+3]*g3;
        } else {
            acc += g0 + g1 + g2 + g3;
        }
    }
    for (; idx < end; ++idx){
        float g = hin[(size_t)csr_src[idx]*DIM + lane];
        if (HAS_EW) g *= ew_csr[idx];
        acc += g;
    }
    outt[(size_t)n*DIM + lane] = acc;
}

// ---------------- LDS staging helpers (256 threads) ----------------
__device__ __forceinline__ void load_tile_T(const float* __restrict__ in, float As[DIM][TPAD],
                                            int m0, int tid){
    // As[k][m] = in[m0+m][k]
    int r = tid >> 2, cq = (tid & 3) * 16;
    bool valid = (m0 + r) < N_NODES;
#pragma unroll
    for (int i = 0; i < 4; i++){
        float4 v = valid ? *(const float4*)&in[(size_t)(m0 + r)*DIM + cq + 4*i]
                         : make_float4(0.f, 0.f, 0.f, 0.f);
        As[cq + 4*i + 0][r] = v.x;
        As[cq + 4*i + 1][r] = v.y;
        As[cq + 4*i + 2][r] = v.z;
        As[cq + 4*i + 3][r] = v.w;
    }
}

__device__ __forceinline__ void load_w(const float* __restrict__ W, float Ws[DIM][TPAD], int tid){
    // Ws[k][n] = W[k*64 + n]
    int kr = tid >> 2, cq = (tid & 3) * 16;
#pragma unroll
    for (int i = 0; i < 4; i++){
        *(float4*)&Ws[kr][cq + 4*i] = *(const float4*)&W[(size_t)kr*DIM + cq + 4*i];
    }
}

// ---------------- fused 2-layer MLP over a 64-node tile ----------------
// OUT[m][n] = act2( relu(IN@W1 + b1) @ W2 + b2 ),  ACT2: 0=relu, 1=sigmoid
template<int ACT2>
__global__ __launch_bounds__(256)
void mlp2_kernel(const float* __restrict__ in, float* __restrict__ outp,
                 const float* __restrict__ W1, const float* __restrict__ b1,
                 const float* __restrict__ W2, const float* __restrict__ b2,
                 long ostride, long obase)
{
    __shared__ __align__(16) float As[DIM][TPAD];
    __shared__ __align__(16) float Ws[DIM][TPAD];
    __shared__ __align__(16) float Ts[DIM][TPAD];
    const int tid = threadIdx.x;
    const int tx = tid & 15, ty = tid >> 4;
    const int m0 = blockIdx.x * 64;

    load_tile_T(in, As, m0, tid);
    load_w(W1, Ws, tid);
    __syncthreads();

    float acc[4][4];
    {
        float4 b1v = *(const float4*)&b1[tx*4];
        float bv[4] = {b1v.x, b1v.y, b1v.z, b1v.w};
#pragma unroll
        for (int i = 0; i < 4; i++)
#pragma unroll
            for (int j = 0; j < 4; j++) acc[i][j] = bv[j];
    }
#pragma unroll 8
    for (int k = 0; k < DIM; k++){
        float4 a = *(const float4*)&As[k][ty*4];
        float4 w = *(const float4*)&Ws[k][tx*4];
        float av[4] = {a.x, a.y, a.z, a.w};
        float wv[4] = {w.x, w.y, w.z, w.w};
#pragma unroll
        for (int i = 0; i < 4; i++)
#pragma unroll
            for (int j = 0; j < 4; j++) acc[i][j] = fmaf(av[i], wv[j], acc[i][j]);
    }
    // relu + transpose-store to Ts[n][m]
#pragma unroll
    for (int j = 0; j < 4; j++){
        float4 v = make_float4(fmaxf(acc[0][j],0.f), fmaxf(acc[1][j],0.f),
                               fmaxf(acc[2][j],0.f), fmaxf(acc[3][j],0.f));
        *(float4*)&Ts[tx*4 + j][ty*4] = v;
    }
    __syncthreads();
    load_w(W2, Ws, tid);
    __syncthreads();

    float acc2[4][4];
    {
        float4 b2v = *(const float4*)&b2[tx*4];
        float bv[4] = {b2v.x, b2v.y, b2v.z, b2v.w};
#pragma unroll
        for (int i = 0; i < 4; i++)
#pragma unroll
            for (int j = 0; j < 4; j++) acc2[i][j] = bv[j];
    }
#pragma unroll 8
    for (int k = 0; k < DIM; k++){
        float4 a = *(const float4*)&Ts[k][ty*4];
        float4 w = *(const float4*)&Ws[k][tx*4];
        float av[4] = {a.x, a.y, a.z, a.w};
        float wv[4] = {w.x, w.y, w.z, w.w};
#pragma unroll
        for (int i = 0; i < 4; i++)
#pragma unroll
            for (int j = 0; j < 4; j++) acc2[i][j] = fmaf(av[i], wv[j], acc2[i][j]);
    }
#pragma unroll
    for (int i = 0; i < 4; i++){
        int m = m0 + ty*4 + i;
        if (m < N_NODES){
            float4 v;
            if (ACT2 == 0){
                v = make_float4(fmaxf(acc2[i][0],0.f), fmaxf(acc2[i][1],0.f),
                                fmaxf(acc2[i][2],0.f), fmaxf(acc2[i][3],0.f));
            } else {
                v = make_float4(sigmoidf_(acc2[i][0]), sigmoidf_(acc2[i][1]),
                                sigmoidf_(acc2[i][2]), sigmoidf_(acc2[i][3]));
            }
            *(float4*)&outp[obase + (size_t)m*ostride + tx*4] = v;
        }
    }
}

// ---------------- node-mask: sigmoid( relu(Z@W1+b1) @ w2 + b2 ) ----------------
__global__ __launch_bounds__(256)
void nm_kernel(const float* __restrict__ Z, float* __restrict__ nm_out,
               const float* __restrict__ W1, const float* __restrict__ b1,
               const float* __restrict__ w2, const float* __restrict__ b2p, int kexp)
{
    __shared__ __align__(16) float As[DIM][TPAD];
    __shared__ __align__(16) float Ws[DIM][TPAD];
    __shared__ __align__(16) float Ts[DIM][TPAD];
    __shared__ float w2s[DIM];
    __shared__ float red[4][DIM];
    const int tid = threadIdx.x;
    const int tx = tid & 15, ty = tid >> 4;
    const int m0 = blockIdx.x * 64;

    load_tile_T(Z, As, m0, tid);
    load_w(W1, Ws, tid);
    if (tid < DIM) w2s[tid] = w2[tid];
    __syncthreads();

    float acc[4][4];
    {
        float4 b1v = *(const float4*)&b1[tx*4];
        float bv[4] = {b1v.x, b1v.y, b1v.z, b1v.w};
#pragma unroll
        for (int i = 0; i < 4; i++)
#pragma unroll
            for (int j = 0; j < 4; j++) acc[i][j] = bv[j];
    }
#pragma unroll 8
    for (int k = 0; k < DIM; k++){
        float4 a = *(const float4*)&As[k][ty*4];
        float4 w = *(const float4*)&Ws[k][tx*4];
        float av[4] = {a.x, a.y, a.z, a.w};
        float wv[4] = {w.x, w.y, w.z, w.w};
#pragma unroll
        for (int i = 0; i < 4; i++)
#pragma unroll
            for (int j = 0; j < 4; j++) acc[i][j] = fmaf(av[i], wv[j], acc[i][j]);
    }
#pragma unroll
    for (int j = 0; j < 4; j++){
        float4 v = make_float4(fmaxf(acc[0][j],0.f), fmaxf(acc[1][j],0.f),
                               fmaxf(acc[2][j],0.f), fmaxf(acc[3][j],0.f));
        *(float4*)&Ts[tx*4 + j][ty*4] = v;
    }
    __syncthreads();
    // dot with w2
    {
        int m = tid & 63, q = tid >> 6;
        float p = 0.f;
#pragma unroll
        for (int kk = 0; kk < 16; kk++) p = fmaf(Ts[q*16 + kk][m], w2s[q*16 + kk], p);
        red[q][m] = p;
    }
    __syncthreads();
    if (tid < DIM){
        int m = m0 + tid;
        if (m < N_NODES){
            float sm = red[0][tid] + red[1][tid] + red[2][tid] + red[3][tid] + *b2p;
            nm_out[(size_t)m*NK + kexp] = sigmoidf_(sm);
        }
    }
}

// ---------------- edge-mask projections (dual GEMM): pt = Z@Wtop, pb = Z@Wbot ----------------
__global__ __launch_bounds__(256)
void em_dual_kernel(const float* __restrict__ Z, const float* __restrict__ Wtop,
                    const float* __restrict__ Wbot, float* __restrict__ pt, float* __restrict__ pb)
{
    __shared__ __align__(16) float As[DIM][TPAD];
    __shared__ __align__(16) float Wt[DIM][TPAD];
    __shared__ __align__(16) float Wb[DIM][TPAD];
    const int tid = threadIdx.x;
    const int tx = tid & 15, ty = tid >> 4;
    const int m0 = blockIdx.x * 64;

    load_tile_T(Z, As, m0, tid);
    load_w(Wtop, Wt, tid);
    load_w(Wbot, Wb, tid);
    __syncthreads();

    float at[4][4] = {}, ab[4][4] = {};
#pragma unroll 8
    for (int k = 0; k < DIM; k++){
        float4 a  = *(const float4*)&As[k][ty*4];
        float4 wt = *(const float4*)&Wt[k][tx*4];
        float4 wb = *(const float4*)&Wb[k][tx*4];
        float av[4] = {a.x, a.y, a.z, a.w};
        float wtv[4] = {wt.x, wt.y, wt.z, wt.w};
        float wbv[4] = {wb.x, wb.y, wb.z, wb.w};
#pragma unroll
        for (int i = 0; i < 4; i++)
#pragma unroll
            for (int j = 0; j < 4; j++){
                at[i][j] = fmaf(av[i], wtv[j], at[i][j]);
                ab[i][j] = fmaf(av[i], wbv[j], ab[i][j]);
            }
    }
#pragma unroll
    for (int i = 0; i < 4; i++){
        int m = m0 + ty*4 + i;
        if (m < N_NODES){
            *(float4*)&pt[(size_t)m*DIM + tx*4] = make_float4(at[i][0], at[i][1], at[i][2], at[i][3]);
            *(float4*)&pb[(size_t)m*DIM + tx*4] = make_float4(ab[i][0], ab[i][1], ab[i][2], ab[i][3]);
        }
    }
}

// ---------------- edge mask: 16 lanes per edge ----------------
__global__ __launch_bounds__(256)
void edge_mask_kernel(const int* __restrict__ ei, const float* __restrict__ pt, const float* __restrict__ pb,
                      const float* __restrict__ b1 /*k-offset*/, const float* __restrict__ w2 /*k-offset*/,
                      const float* __restrict__ b2p /*k-offset*/, float* __restrict__ em_out, int k)
{
    const int sub = threadIdx.x & 15;
    const float4 w2v = *(const float4*)&w2[sub*4];
    const float4 b1v = *(const float4*)&b1[sub*4];
    const float b2 = *b2p;
    const int estart = blockIdx.x*16 + (threadIdx.x >> 4);
    const int estride = gridDim.x * 16;
    for (int e = estart; e < N_EDGES; e += estride){
        int s = ei[e], d = ei[N_EDGES + e];
        float4 a  = *(const float4*)&pt[(size_t)s*DIM + sub*4];
        float4 bb = *(const float4*)&pb[(size_t)d*DIM + sub*4];
        float h0 = fmaxf(a.x + bb.x + b1v.x, 0.f);
        float h1 = fmaxf(a.y + bb.y + b1v.y, 0.f);
        float h2 = fmaxf(a.z + bb.z + b1v.z, 0.f);
        float h3 = fmaxf(a.w + bb.w + b1v.w, 0.f);
        float p = h0*w2v.x + h1*w2v.y + h2*w2v.z + h3*w2v.w;
        p += __shfl_xor(p, 1, 16);
        p += __shfl_xor(p, 2, 16);
        p += __shfl_xor(p, 4, 16);
        p += __shfl_xor(p, 8, 16);
        if (sub == 0) em_out[(size_t)e*NK + k] = sigmoidf_(p + b2);
    }
}

// ---------------- masked_x for expert k (vectorized) ----------------
__global__ void build_h0_kernel(const float* __restrict__ x, const float* __restrict__ nm_out,
                                const float* __restrict__ fm_out, float* __restrict__ h0, int k)
{
    int t4 = blockIdx.x*256 + threadIdx.x;
    if (t4 < N_NODES*16){
        int n = t4 >> 4, c = (t4 & 15) * 4;
        float nm = nm_out[(size_t)n*NK + k];
        float4 xv = *(const float4*)&x[(size_t)n*DIM + c];
        float4 fv = *(const float4*)&fm_out[((size_t)n*NK + k)*DIM + c];
        float4 o = make_float4(xv.x*nm*fv.x, xv.y*nm*fv.y, xv.z*nm*fv.z, xv.w*nm*fv.w);
        *(float4*)&h0[(size_t)n*DIM + c] = o;
    }
}

// ---------------- pooling (batch is sorted -> binary search segment) ----------------
__device__ __forceinline__ int lower_bound_(const int* a, int n, int v){
    int lo = 0, hi = n;
    while (lo < hi){ int m = (lo + hi) >> 1; if (a[m] < v) lo = m + 1; else hi = m; }
    return lo;
}

__global__ __launch_bounds__(64)
void pool_orig_kernel(const float* __restrict__ h, const int* __restrict__ batch, float* __restrict__ out){
    int b = blockIdx.x, lane = threadIdx.x;
    int lo = lower_bound_(batch, N_NODES, b);
    int hi = lower_bound_(batch, N_NODES, b+1);
    float s = 0.f;
    int n = lo;
    for (; n + 4 <= hi; n += 4){
        s += h[(size_t)n*DIM + lane] + h[(size_t)(n+1)*DIM + lane]
           + h[(size_t)(n+2)*DIM + lane] + h[(size_t)(n+3)*DIM + lane];
    }
    for (; n < hi; ++n) s += h[(size_t)n*DIM + lane];
    out[(size_t)b*DIM + lane] = s / fmaxf((float)(hi - lo), 1.f);
}

__global__ __launch_bounds__(64)
void pool_expert_kernel(const float* __restrict__ h, const int* __restrict__ batch,
                        const float* __restrict__ clfW /*k-offset [64,10]*/, const float* __restrict__ clfb,
                        float* __restrict__ out_logits, float* __restrict__ out_hst, int k)
{
    __shared__ float ms[DIM];
    int b = blockIdx.x, lane = threadIdx.x;
    int lo = lower_bound_(batch, N_NODES, b);
    int hi = lower_bound_(batch, N_NODES, b+1);
    float s = 0.f;
    int n = lo;
    for (; n + 4 <= hi; n += 4){
        s += h[(size_t)n*DIM + lane] + h[(size_t)(n+1)*DIM + lane]
           + h[(size_t)(n+2)*DIM + lane] + h[(size_t)(n+3)*DIM + lane];
    }
    for (; n < hi; ++n) s += h[(size_t)n*DIM + lane];
    float m = s / fmaxf((float)(hi - lo), 1.f);
    out_hst[((size_t)b*NK + k)*DIM + lane] = m;
    ms[lane] = m;
    __syncthreads();
    if (lane < NC){
        float a = clfb[lane];
#pragma unroll
        for (int j = 0; j < DIM; j++) a = fmaf(ms[j], clfW[j*NC + lane], a);
        out_logits[((size_t)b*NK + k)*NC + lane] = a;
    }
}

// ---------------- launch ----------------
extern "C" void kernel_launch(void* const* d_in, const int* in_sizes, int n_in,
                              void* d_out, int out_size, void* d_ws, size_t ws_size,
                              hipStream_t stream)
{
    const float* x     = (const float*)d_in[0];
    const int*   ei    = (const int*)  d_in[1];
    const int*   batch = (const int*)  d_in[2];
    const float* ceW1 = (const float*)d_in[3];
    const float* ceb1 = (const float*)d_in[4];
    const float* ceW2 = (const float*)d_in[5];
    const float* ceb2 = (const float*)d_in[6];
    const float* ceeps= (const float*)d_in[7];
    const float* clW1 = (const float*)d_in[8];
    const float* clb1 = (const float*)d_in[9];
    const float* clW2 = (const float*)d_in[10];
    const float* clb2 = (const float*)d_in[11];
    const float* cleps= (const float*)d_in[12];
    const float* nmW1 = (const float*)d_in[13];
    const float* nmb1 = (const float*)d_in[14];
    const float* nmW2 = (const float*)d_in[15];
    const float* nmb2 = (const float*)d_in[16];
    const float* emW1 = (const float*)d_in[17];
    const float* emb1 = (const float*)d_in[18];
    const float* emW2 = (const float*)d_in[19];
    const float* emb2 = (const float*)d_in[20];
    const float* fmW1 = (const float*)d_in[21];
    const float* fmb1 = (const float*)d_in[22];
    const float* fmW2 = (const float*)d_in[23];
    const float* fmb2 = (const float*)d_in[24];
    const float* clfW = (const float*)d_in[25];
    const float* clfb = (const float*)d_in[26];

    // output layout (f32, flat, return order)
    float* out        = (float*)d_out;
    float* out_logits = out;                       // [B,K,C]     10240
    float* out_hst    = out + 10240;               // [B,K,H]     65536
    float* out_horig  = out + 75776;               // [B,H]       16384
    float* nm_out     = out + 92160;               // [N,K]       200000
    float* em_out     = out + 292160;              // [E,K]       3200000
    float* fm_out     = out + 3492160;             // [N,K,F]     12800000

    // workspace layout
    int* rowptr  = (int*)d_ws;                     // N+1
    int* cursor  = rowptr + (N_NODES + 1);         // N
    int* deg     = cursor + N_NODES;               // N
    int* csr_src = deg + N_NODES;                  // E
    int* csr_eid = csr_src + N_EDGES;              // E
    int* bsum    = csr_eid + N_EDGES;              // 256
    int* boff    = bsum + 256;                     // 256
    size_t int_count = (size_t)(N_NODES+1) + N_NODES + N_NODES + N_EDGES + N_EDGES + 512;
    int_count = (int_count + 3) & ~(size_t)3;
    float* hA = (float*)(((int*)d_ws) + int_count);   // N*64   (Z lives here after CE)
    float* hB = hA + (size_t)N_NODES*DIM;             // N*64
    float* C1 = hB + (size_t)N_NODES*DIM;             // N*64
    float* C2 = C1 + (size_t)N_NODES*DIM;             // N*64
    float* ew_csr = C2 + (size_t)N_NODES*DIM;         // E

    const int GT = (N_NODES + 63) / 64;   // 782 tiles

    // ---- CSR build ----
    hipMemsetAsync(deg, 0, N_NODES*sizeof(int), stream);
    deg_hist_kernel<<<(N_EDGES+255)/256, 256, 0, stream>>>(ei, deg);
    scan_p1<<<SCAN_BLKS, 256, 0, stream>>>(deg, rowptr, bsum);
    scan_p2<<<1, 256, 0, stream>>>(bsum, boff);
    scan_p3<<<SCAN_BLKS, 256, 0, stream>>>(rowptr, boff, cursor);
    csr_fill_kernel<<<(N_EDGES+255)/256, 256, 0, stream>>>(ei, cursor, csr_src, csr_eid);

    // ---- causal encoder GIN (3 layers): x -> hA -> hB -> hA (Z=hA) ----
    agg_kernel<false><<<(N_NODES+3)/4, 256, 0, stream>>>(x,  C1, rowptr, csr_src, nullptr, ceeps + 0);
    mlp2_kernel<0><<<GT, 256, 0, stream>>>(C1, hA, ceW1 + 0*DIM*DIM, ceb1 + 0*DIM,
                                           ceW2 + 0*DIM*DIM, ceb2 + 0*DIM, DIM, 0);
    agg_kernel<false><<<(N_NODES+3)/4, 256, 0, stream>>>(hA, C1, rowptr, csr_src, nullptr, ceeps + 1);
    mlp2_kernel<0><<<GT, 256, 0, stream>>>(C1, hB, ceW1 + 1*DIM*DIM, ceb1 + 1*DIM,
                                           ceW2 + 1*DIM*DIM, ceb2 + 1*DIM, DIM, 0);
    agg_kernel<false><<<(N_NODES+3)/4, 256, 0, stream>>>(hB, C1, rowptr, csr_src, nullptr, ceeps + 2);
    mlp2_kernel<0><<<GT, 256, 0, stream>>>(C1, hA, ceW1 + 2*DIM*DIM, ceb1 + 2*DIM,
                                           ceW2 + 2*DIM*DIM, ceb2 + 2*DIM, DIM, 0);
    const float* Z = hA;

    // ---- h_orig pooling ----
    pool_orig_kernel<<<NB, 64, 0, stream>>>(Z, batch, out_horig);

    // ---- per-expert ----
    for (int k = 0; k < NK; ++k){
        // node mask
        nm_kernel<<<GT, 256, 0, stream>>>(Z, nm_out, nmW1 + (size_t)k*DIM*DIM, nmb1 + k*DIM,
                                          nmW2 + k*DIM, nmb2 + k, k);
        // feature mask
        mlp2_kernel<1><<<GT, 256, 0, stream>>>(Z, fm_out, fmW1 + (size_t)k*DIM*DIM, fmb1 + k*DIM,
                                               fmW2 + (size_t)k*DIM*DIM, fmb2 + k*DIM,
                                               (long)NK*DIM, (long)k*DIM);
        // edge mask projections + per-edge mask
        em_dual_kernel<<<GT, 256, 0, stream>>>(Z, emW1 + (size_t)k*2*DIM*DIM,
                                               emW1 + (size_t)k*2*DIM*DIM + DIM*DIM, hB, C1);
        edge_mask_kernel<<<4096, 256, 0, stream>>>(ei, hB, C1, emb1 + k*DIM, emW2 + k*DIM,
                                                   emb2 + k, em_out, k);
        gather_ew_kernel<<<(N_EDGES+255)/256, 256, 0, stream>>>(csr_eid, em_out, ew_csr, k);
        // masked input
        build_h0_kernel<<<(N_NODES*16+255)/256, 256, 0, stream>>>(x, nm_out, fm_out, C2, k);
        // classifier GIN (3 layers): C2 -> hB -> hB -> C2
        agg_kernel<true><<<(N_NODES+3)/4, 256, 0, stream>>>(C2, C1, rowptr, csr_src, ew_csr, cleps + 0);
        mlp2_kernel<0><<<GT, 256, 0, stream>>>(C1, hB, clW1 + 0*DIM*DIM, clb1 + 0*DIM,
                                               clW2 + 0*DIM*DIM, clb2 + 0*DIM, DIM, 0);
        agg_kernel<true><<<(N_NODES+3)/4, 256, 0, stream>>>(hB, C1, rowptr, csr_src, ew_csr, cleps + 1);
        mlp2_kernel<0><<<GT, 256, 0, stream>>>(C1, hB, clW1 + 1*DIM*DIM, clb1 + 1*DIM,
                                               clW2 + 1*DIM*DIM, clb2 + 1*DIM, DIM, 0);
        agg_kernel<true><<<(N_NODES+3)/4, 256, 0, stream>>>(hB, C1, rowptr, csr_src, ew_csr, cleps + 2);
        mlp2_kernel<0><<<GT, 256, 0, stream>>>(C1, C2, clW1 + 2*DIM*DIM, clb1 + 2*DIM,
                                               clW2 + 2*DIM*DIM, clb2 + 2*DIM, DIM, 0);
        pool_expert_kernel<<<NB, 64, 0, stream>>>(C2, batch, clfW + (size_t)k*DIM*NC, clfb + k*NC,
                                                  out_logits, out_hst, k);
    }
}

// Round 4
// 1409.598 us; speedup vs baseline: 1.9832x; 1.2853x over previous
//
#include <hip/hip_runtime.h>
#include <math.h>

#define N_NODES 50000
#define N_EDGES 800000
#define DIM 64
#define NB 256
#define NK 4
#define NC 10
#define TPAD 68
#define SCAN_BLKS 196  // ceil(50000/256)

typedef unsigned int uint_;
typedef unsigned short ushort_;

__device__ __forceinline__ float sigmoidf_(float x){ return 1.f/(1.f+__expf(-x)); }
__device__ __forceinline__ float bf2f(ushort_ v){ return __uint_as_float(((uint_)v)<<16); }
__device__ __forceinline__ float bflo(uint_ u){ return __uint_as_float(u<<16); }
__device__ __forceinline__ float bfhi(uint_ u){ return __uint_as_float(u & 0xFFFF0000u); }
__device__ __forceinline__ ushort_ f2bf(float f){
    uint_ u = __float_as_uint(f);
    u = (u + 0x7FFFu + ((u>>16)&1u)) >> 16;
    return (ushort_)u;
}

// ---------------- CSR build ----------------
__global__ void deg_hist_kernel(const int* __restrict__ ei, int* __restrict__ deg){
    int e = blockIdx.x*256 + threadIdx.x;
    if (e < N_EDGES) atomicAdd(&deg[ei[N_EDGES + e]], 1);
}

__global__ __launch_bounds__(256)
void scan_p1(const int* __restrict__ deg, int* __restrict__ rowptr, int* __restrict__ bsum){
    __shared__ int s[256];
    int tid = threadIdx.x;
    int i = blockIdx.x*256 + tid;
    int v = (i < N_NODES) ? deg[i] : 0;
    s[tid] = v;
    __syncthreads();
    for (int off = 1; off < 256; off <<= 1){
        int t = (tid >= off) ? s[tid - off] : 0;
        __syncthreads();
        s[tid] += t;
        __syncthreads();
    }
    if (i < N_NODES) rowptr[i] = s[tid] - v;
    if (tid == 255) bsum[blockIdx.x] = s[255];
}

__global__ __launch_bounds__(256)
void scan_p2(const int* __restrict__ bsum, int* __restrict__ boff){
    __shared__ int s[256];
    int tid = threadIdx.x;
    int v = (tid < SCAN_BLKS) ? bsum[tid] : 0;
    s[tid] = v;
    __syncthreads();
    for (int off = 1; off < 256; off <<= 1){
        int t = (tid >= off) ? s[tid - off] : 0;
        __syncthreads();
        s[tid] += t;
        __syncthreads();
    }
    boff[tid] = s[tid] - v;
}

__global__ __launch_bounds__(256)
void scan_p3(int* __restrict__ rowptr, const int* __restrict__ boff, int* __restrict__ cursor){
    int i = blockIdx.x*256 + threadIdx.x;
    if (i < N_NODES){
        int r = rowptr[i] + boff[blockIdx.x];
        rowptr[i] = r;
        cursor[i] = r;
    }
    if (i == 0) rowptr[N_NODES] = N_EDGES;
}

__global__ void csr_fill_kernel(const int* __restrict__ ei, int* __restrict__ cursor,
                                int* __restrict__ csr_src, int* __restrict__ csr_eid){
    int e = blockIdx.x*256 + threadIdx.x;
    if (e < N_EDGES){
        int d = ei[N_EDGES + e];
        int pos = atomicAdd(&cursor[d], 1);
        csr_src[pos] = ei[e];
        csr_eid[pos] = e;
    }
}

// ---------------- f32 -> bf16 copy ----------------
__global__ void tobf16_kernel(const float* __restrict__ x, ushort_* __restrict__ o){
    int i = blockIdx.x*256 + threadIdx.x;
    if (i < N_NODES*DIM/4){
        float4 v = *(const float4*)&x[(size_t)i*4];
        ushort4 o4;
        o4.x = f2bf(v.x); o4.y = f2bf(v.y); o4.z = f2bf(v.z); o4.w = f2bf(v.w);
        *(ushort4*)&o[(size_t)i*4] = o4;
    }
}

// ---------------- aggregation: t = (1+eps)*h + sum_j [ew_j] h_j  (wave per node, bf16 in) ----------------
template<bool HAS_EW>
__global__ __launch_bounds__(256)
void agg16_kernel(const ushort_* __restrict__ hin, float* __restrict__ outt,
                  const int* __restrict__ rowptr, const int* __restrict__ csr_src,
                  const ushort_* __restrict__ ew_csr, const float* __restrict__ eps_p)
{
    const int n = blockIdx.x*4 + (threadIdx.x >> 6);
    if (n >= N_NODES) return;
    const int lane = threadIdx.x & 63;
    const float epv = 1.0f + *eps_p;
    float acc = epv * bf2f(hin[(size_t)n*DIM + lane]);
    int idx = rowptr[n];
    const int end = rowptr[n+1];
    for (; idx + 4 <= end; idx += 4){
        int s0 = csr_src[idx+0], s1 = csr_src[idx+1], s2 = csr_src[idx+2], s3 = csr_src[idx+3];
        float g0 = bf2f(hin[(size_t)s0*DIM + lane]), g1 = bf2f(hin[(size_t)s1*DIM + lane]);
        float g2 = bf2f(hin[(size_t)s2*DIM + lane]), g3 = bf2f(hin[(size_t)s3*DIM + lane]);
        if (HAS_EW){
            acc += bf2f(ew_csr[idx+0])*g0 + bf2f(ew_csr[idx+1])*g1
                 + bf2f(ew_csr[idx+2])*g2 + bf2f(ew_csr[idx+3])*g3;
        } else {
            acc += g0 + g1 + g2 + g3;
        }
    }
    for (; idx < end; ++idx){
        float g = bf2f(hin[(size_t)csr_src[idx]*DIM + lane]);
        if (HAS_EW) g *= bf2f(ew_csr[idx]);
        acc += g;
    }
    outt[(size_t)n*DIM + lane] = acc;
}

// ---------------- LDS staging helpers (256 threads) ----------------
__device__ __forceinline__ void load_tileT_f32(const float* __restrict__ in, float As[DIM][TPAD],
                                               int m0, int tid){
    int r = tid >> 2, cq = (tid & 3) * 16;
    bool valid = (m0 + r) < N_NODES;
#pragma unroll
    for (int i = 0; i < 4; i++){
        float4 v = valid ? *(const float4*)&in[(size_t)(m0 + r)*DIM + cq + 4*i]
                         : make_float4(0.f, 0.f, 0.f, 0.f);
        As[cq + 4*i + 0][r] = v.x;
        As[cq + 4*i + 1][r] = v.y;
        As[cq + 4*i + 2][r] = v.z;
        As[cq + 4*i + 3][r] = v.w;
    }
}

__device__ __forceinline__ void load_tileT_b16(const ushort_* __restrict__ in, float As[DIM][TPAD],
                                               int m0, int tid){
    int r = tid >> 2, cq = (tid & 3) * 16;
    bool valid = (m0 + r) < N_NODES;
    uint_ us[8] = {0,0,0,0,0,0,0,0};
    if (valid){
        const uint_* p = (const uint_*)&in[(size_t)(m0 + r)*DIM + cq];
        uint4 a = *(const uint4*)p;
        uint4 b = *(const uint4*)(p + 4);
        us[0]=a.x; us[1]=a.y; us[2]=a.z; us[3]=a.w;
        us[4]=b.x; us[5]=b.y; us[6]=b.z; us[7]=b.w;
    }
#pragma unroll
    for (int w = 0; w < 8; w++){
        As[cq + 2*w + 0][r] = bflo(us[w]);
        As[cq + 2*w + 1][r] = bfhi(us[w]);
    }
}

__device__ __forceinline__ void load_w(const float* __restrict__ W, float Ws[DIM][TPAD], int tid){
    int kr = tid >> 2, cq = (tid & 3) * 16;
#pragma unroll
    for (int i = 0; i < 4; i++){
        *(float4*)&Ws[kr][cq + 4*i] = *(const float4*)&W[(size_t)kr*DIM + cq + 4*i];
    }
}

// ---------------- fused 2-layer MLP over a 64-node tile ----------------
// TIN16: input bf16?  ACT2: 0=relu 1=sigmoid  TOUT16: output bf16?
template<int TIN16, int ACT2, int TOUT16>
__global__ __launch_bounds__(256)
void mlp2_kernel(const void* __restrict__ inp, void* __restrict__ outp,
                 const float* __restrict__ W1, const float* __restrict__ b1,
                 const float* __restrict__ W2, const float* __restrict__ b2,
                 long ostride, long obase)
{
    __shared__ __align__(16) float As[DIM][TPAD];
    __shared__ __align__(16) float Ws[DIM][TPAD];
    __shared__ __align__(16) float Ts[DIM][TPAD];
    const int tid = threadIdx.x;
    const int tx = tid & 15, ty = tid >> 4;
    const int m0 = blockIdx.x * 64;

    if (TIN16) load_tileT_b16((const ushort_*)inp, As, m0, tid);
    else       load_tileT_f32((const float*)inp, As, m0, tid);
    load_w(W1, Ws, tid);
    __syncthreads();

    float acc[4][4];
    {
        float4 b1v = *(const float4*)&b1[tx*4];
        float bv[4] = {b1v.x, b1v.y, b1v.z, b1v.w};
#pragma unroll
        for (int i = 0; i < 4; i++)
#pragma unroll
            for (int j = 0; j < 4; j++) acc[i][j] = bv[j];
    }
#pragma unroll 8
    for (int k = 0; k < DIM; k++){
        float4 a = *(const float4*)&As[k][ty*4];
        float4 w = *(const float4*)&Ws[k][tx*4];
        float av[4] = {a.x, a.y, a.z, a.w};
        float wv[4] = {w.x, w.y, w.z, w.w};
#pragma unroll
        for (int i = 0; i < 4; i++)
#pragma unroll
            for (int j = 0; j < 4; j++) acc[i][j] = fmaf(av[i], wv[j], acc[i][j]);
    }
#pragma unroll
    for (int j = 0; j < 4; j++){
        float4 v = make_float4(fmaxf(acc[0][j],0.f), fmaxf(acc[1][j],0.f),
                               fmaxf(acc[2][j],0.f), fmaxf(acc[3][j],0.f));
        *(float4*)&Ts[tx*4 + j][ty*4] = v;
    }
    __syncthreads();
    load_w(W2, Ws, tid);
    __syncthreads();

    float acc2[4][4];
    {
        float4 b2v = *(const float4*)&b2[tx*4];
        float bv[4] = {b2v.x, b2v.y, b2v.z, b2v.w};
#pragma unroll
        for (int i = 0; i < 4; i++)
#pragma unroll
            for (int j = 0; j < 4; j++) acc2[i][j] = bv[j];
    }
#pragma unroll 8
    for (int k = 0; k < DIM; k++){
        float4 a = *(const float4*)&Ts[k][ty*4];
        float4 w = *(const float4*)&Ws[k][tx*4];
        float av[4] = {a.x, a.y, a.z, a.w};
        float wv[4] = {w.x, w.y, w.z, w.w};
#pragma unroll
        for (int i = 0; i < 4; i++)
#pragma unroll
            for (int j = 0; j < 4; j++) acc2[i][j] = fmaf(av[i], wv[j], acc2[i][j]);
    }
#pragma unroll
    for (int i = 0; i < 4; i++){
        int m = m0 + ty*4 + i;
        if (m < N_NODES){
            float v0, v1, v2, v3;
            if (ACT2 == 0){
                v0 = fmaxf(acc2[i][0],0.f); v1 = fmaxf(acc2[i][1],0.f);
                v2 = fmaxf(acc2[i][2],0.f); v3 = fmaxf(acc2[i][3],0.f);
            } else {
                v0 = sigmoidf_(acc2[i][0]); v1 = sigmoidf_(acc2[i][1]);
                v2 = sigmoidf_(acc2[i][2]); v3 = sigmoidf_(acc2[i][3]);
            }
            if (TOUT16){
                ushort4 o;
                o.x = f2bf(v0); o.y = f2bf(v1); o.z = f2bf(v2); o.w = f2bf(v3);
                *(ushort4*)&((ushort_*)outp)[obase + (size_t)m*ostride + tx*4] = o;
            } else {
                *(float4*)&((float*)outp)[obase + (size_t)m*ostride + tx*4] =
                    make_float4(v0, v1, v2, v3);
            }
        }
    }
}

// ---------------- node-mask: sigmoid( relu(Z@W1+b1) @ w2 + b2 ) ----------------
__global__ __launch_bounds__(256)
void nm_kernel(const ushort_* __restrict__ Z16, float* __restrict__ nm_out,
               const float* __restrict__ W1, const float* __restrict__ b1,
               const float* __restrict__ w2, const float* __restrict__ b2p, int kexp)
{
    __shared__ __align__(16) float As[DIM][TPAD];
    __shared__ __align__(16) float Ws[DIM][TPAD];
    __shared__ __align__(16) float Ts[DIM][TPAD];
    __shared__ float w2s[DIM];
    __shared__ float red[4][DIM];
    const int tid = threadIdx.x;
    const int tx = tid & 15, ty = tid >> 4;
    const int m0 = blockIdx.x * 64;

    load_tileT_b16(Z16, As, m0, tid);
    load_w(W1, Ws, tid);
    if (tid < DIM) w2s[tid] = w2[tid];
    __syncthreads();

    float acc[4][4];
    {
        float4 b1v = *(const float4*)&b1[tx*4];
        float bv[4] = {b1v.x, b1v.y, b1v.z, b1v.w};
#pragma unroll
        for (int i = 0; i < 4; i++)
#pragma unroll
            for (int j = 0; j < 4; j++) acc[i][j] = bv[j];
    }
#pragma unroll 8
    for (int k = 0; k < DIM; k++){
        float4 a = *(const float4*)&As[k][ty*4];
        float4 w = *(const float4*)&Ws[k][tx*4];
        float av[4] = {a.x, a.y, a.z, a.w};
        float wv[4] = {w.x, w.y, w.z, w.w};
#pragma unroll
        for (int i = 0; i < 4; i++)
#pragma unroll
            for (int j = 0; j < 4; j++) acc[i][j] = fmaf(av[i], wv[j], acc[i][j]);
    }
#pragma unroll
    for (int j = 0; j < 4; j++){
        float4 v = make_float4(fmaxf(acc[0][j],0.f), fmaxf(acc[1][j],0.f),
                               fmaxf(acc[2][j],0.f), fmaxf(acc[3][j],0.f));
        *(float4*)&Ts[tx*4 + j][ty*4] = v;
    }
    __syncthreads();
    {
        int m = tid & 63, q = tid >> 6;
        float p = 0.f;
#pragma unroll
        for (int kk = 0; kk < 16; kk++) p = fmaf(Ts[q*16 + kk][m], w2s[q*16 + kk], p);
        red[q][m] = p;
    }
    __syncthreads();
    if (tid < DIM){
        int m = m0 + tid;
        if (m < N_NODES){
            float sm = red[0][tid] + red[1][tid] + red[2][tid] + red[3][tid] + *b2p;
            nm_out[(size_t)m*NK + kexp] = sigmoidf_(sm);
        }
    }
}

// ---------------- edge-mask projections for ALL experts: grid (tiles, 8) ----------------
// slice s: k = s>>1, side = s&1;  out[n][k*64+c] = (Z @ emW1_k_side)[n][c]  (bf16)
__global__ __launch_bounds__(256)
void em_proj4_kernel(const ushort_* __restrict__ Z16, const float* __restrict__ emW1,
                     ushort_* __restrict__ pt4, ushort_* __restrict__ pb4)
{
    __shared__ __align__(16) float As[DIM][TPAD];
    __shared__ __align__(16) float Ws[DIM][TPAD];
    const int s = blockIdx.y;
    const int k = s >> 1, side = s & 1;
    const float* W = emW1 + ((size_t)k*2 + side)*DIM*DIM;
    ushort_* outp = side ? pb4 : pt4;
    const int tid = threadIdx.x;
    const int tx = tid & 15, ty = tid >> 4;
    const int m0 = blockIdx.x * 64;

    load_tileT_b16(Z16, As, m0, tid);
    load_w(W, Ws, tid);
    __syncthreads();

    float acc[4][4] = {};
#pragma unroll 8
    for (int kk = 0; kk < DIM; kk++){
        float4 a = *(const float4*)&As[kk][ty*4];
        float4 w = *(const float4*)&Ws[kk][tx*4];
        float av[4] = {a.x, a.y, a.z, a.w};
        float wv[4] = {w.x, w.y, w.z, w.w};
#pragma unroll
        for (int i = 0; i < 4; i++)
#pragma unroll
            for (int j = 0; j < 4; j++) acc[i][j] = fmaf(av[i], wv[j], acc[i][j]);
    }
#pragma unroll
    for (int i = 0; i < 4; i++){
        int m = m0 + ty*4 + i;
        if (m < N_NODES){
            ushort4 o;
            o.x = f2bf(acc[i][0]); o.y = f2bf(acc[i][1]);
            o.z = f2bf(acc[i][2]); o.w = f2bf(acc[i][3]);
            *(ushort4*)&outp[(size_t)m*(NK*DIM) + k*DIM + tx*4] = o;
        }
    }
}

// ---------------- edge mask, all 4 experts, wave-per-node over CSR ----------------
// lane = (k, fq): k = lane>>4, fq = lane&15. pb[dst] held in registers; pt[src] gathered.
__global__ __launch_bounds__(256)
void edge_mask16_kernel(const ushort_* __restrict__ pt4, const ushort_* __restrict__ pb4,
                        const int* __restrict__ rowptr, const int* __restrict__ csr_src,
                        const int* __restrict__ csr_eid,
                        const float* __restrict__ emb1, const float* __restrict__ emW2,
                        const float* __restrict__ emb2,
                        float* __restrict__ em_out, ushort_* __restrict__ ew_csr)
{
    const int n = blockIdx.x*4 + (threadIdx.x >> 6);
    if (n >= N_NODES) return;
    const int lane = threadIdx.x & 63;
    const int k = lane >> 4, fq = lane & 15;
    const float4 w2v = *(const float4*)&emW2[k*DIM + fq*4];
    const float4 b1v = *(const float4*)&emb1[k*DIM + fq*4];
    const float b2 = emb2[k];
    uint2 pbu = *(const uint2*)&pb4[(size_t)n*(NK*DIM) + k*DIM + fq*4];
    const float pre0 = bflo(pbu.x) + b1v.x;
    const float pre1 = bfhi(pbu.x) + b1v.y;
    const float pre2 = bflo(pbu.y) + b1v.z;
    const float pre3 = bfhi(pbu.y) + b1v.w;
    int i = rowptr[n];
    const int end = rowptr[n+1];
    for (; i + 2 <= end; i += 2){
        int s0 = csr_src[i], s1 = csr_src[i+1];
        uint2 a0 = *(const uint2*)&pt4[(size_t)s0*(NK*DIM) + k*DIM + fq*4];
        uint2 a1 = *(const uint2*)&pt4[(size_t)s1*(NK*DIM) + k*DIM + fq*4];
        float p0 = fmaxf(bflo(a0.x) + pre0, 0.f)*w2v.x + fmaxf(bfhi(a0.x) + pre1, 0.f)*w2v.y
                 + fmaxf(bflo(a0.y) + pre2, 0.f)*w2v.z + fmaxf(bfhi(a0.y) + pre3, 0.f)*w2v.w;
        float p1 = fmaxf(bflo(a1.x) + pre0, 0.f)*w2v.x + fmaxf(bfhi(a1.x) + pre1, 0.f)*w2v.y
                 + fmaxf(bflo(a1.y) + pre2, 0.f)*w2v.z + fmaxf(bfhi(a1.y) + pre3, 0.f)*w2v.w;
        p0 += __shfl_xor(p0, 1, 16); p1 += __shfl_xor(p1, 1, 16);
        p0 += __shfl_xor(p0, 2, 16); p1 += __shfl_xor(p1, 2, 16);
        p0 += __shfl_xor(p0, 4, 16); p1 += __shfl_xor(p1, 4, 16);
        p0 += __shfl_xor(p0, 8, 16); p1 += __shfl_xor(p1, 8, 16);
        if (fq == 0){
            float m0v = sigmoidf_(p0 + b2);
            float m1v = sigmoidf_(p1 + b2);
            em_out[(size_t)csr_eid[i]*NK + k]   = m0v;
            em_out[(size_t)csr_eid[i+1]*NK + k] = m1v;
            ew_csr[(size_t)k*N_EDGES + i]     = f2bf(m0v);
            ew_csr[(size_t)k*N_EDGES + i + 1] = f2bf(m1v);
        }
    }
    for (; i < end; ++i){
        int s0 = csr_src[i];
        uint2 a0 = *(const uint2*)&pt4[(size_t)s0*(NK*DIM) + k*DIM + fq*4];
        float p0 = fmaxf(bflo(a0.x) + pre0, 0.f)*w2v.x + fmaxf(bfhi(a0.x) + pre1, 0.f)*w2v.y
                 + fmaxf(bflo(a0.y) + pre2, 0.f)*w2v.z + fmaxf(bfhi(a0.y) + pre3, 0.f)*w2v.w;
        p0 += __shfl_xor(p0, 1, 16);
        p0 += __shfl_xor(p0, 2, 16);
        p0 += __shfl_xor(p0, 4, 16);
        p0 += __shfl_xor(p0, 8, 16);
        if (fq == 0){
            float m0v = sigmoidf_(p0 + b2);
            em_out[(size_t)csr_eid[i]*NK + k] = m0v;
            ew_csr[(size_t)k*N_EDGES + i] = f2bf(m0v);
        }
    }
}

// ---------------- masked_x for expert k (bf16 out) ----------------
__global__ void build_h0_kernel(const float* __restrict__ x, const float* __restrict__ nm_out,
                                const float* __restrict__ fm_out, ushort_* __restrict__ h0, int k)
{
    int t4 = blockIdx.x*256 + threadIdx.x;
    if (t4 < N_NODES*16){
        int n = t4 >> 4, c = (t4 & 15) * 4;
        float nm = nm_out[(size_t)n*NK + k];
        float4 xv = *(const float4*)&x[(size_t)n*DIM + c];
        float4 fv = *(const float4*)&fm_out[((size_t)n*NK + k)*DIM + c];
        ushort4 o;
        o.x = f2bf(xv.x*nm*fv.x); o.y = f2bf(xv.y*nm*fv.y);
        o.z = f2bf(xv.z*nm*fv.z); o.w = f2bf(xv.w*nm*fv.w);
        *(ushort4*)&h0[(size_t)n*DIM + c] = o;
    }
}

// ---------------- pooling (batch is sorted -> binary search segment) ----------------
__device__ __forceinline__ int lower_bound_(const int* a, int n, int v){
    int lo = 0, hi = n;
    while (lo < hi){ int m = (lo + hi) >> 1; if (a[m] < v) lo = m + 1; else hi = m; }
    return lo;
}

__global__ __launch_bounds__(64)
void pool_orig_kernel(const ushort_* __restrict__ h, const int* __restrict__ batch, float* __restrict__ out){
    int b = blockIdx.x, lane = threadIdx.x;
    int lo = lower_bound_(batch, N_NODES, b);
    int hi = lower_bound_(batch, N_NODES, b+1);
    float s = 0.f;
    int n = lo;
    for (; n + 4 <= hi; n += 4){
        s += bf2f(h[(size_t)n*DIM + lane]) + bf2f(h[(size_t)(n+1)*DIM + lane])
           + bf2f(h[(size_t)(n+2)*DIM + lane]) + bf2f(h[(size_t)(n+3)*DIM + lane]);
    }
    for (; n < hi; ++n) s += bf2f(h[(size_t)n*DIM + lane]);
    out[(size_t)b*DIM + lane] = s / fmaxf((float)(hi - lo), 1.f);
}

__global__ __launch_bounds__(64)
void pool_expert_kernel(const ushort_* __restrict__ h, const int* __restrict__ batch,
                        const float* __restrict__ clfW, const float* __restrict__ clfb,
                        float* __restrict__ out_logits, float* __restrict__ out_hst, int k)
{
    __shared__ float ms[DIM];
    int b = blockIdx.x, lane = threadIdx.x;
    int lo = lower_bound_(batch, N_NODES, b);
    int hi = lower_bound_(batch, N_NODES, b+1);
    float s = 0.f;
    int n = lo;
    for (; n + 4 <= hi; n += 4){
        s += bf2f(h[(size_t)n*DIM + lane]) + bf2f(h[(size_t)(n+1)*DIM + lane])
           + bf2f(h[(size_t)(n+2)*DIM + lane]) + bf2f(h[(size_t)(n+3)*DIM + lane]);
    }
    for (; n < hi; ++n) s += bf2f(h[(size_t)n*DIM + lane]);
    float m = s / fmaxf((float)(hi - lo), 1.f);
    out_hst[((size_t)b*NK + k)*DIM + lane] = m;
    ms[lane] = m;
    __syncthreads();
    if (lane < NC){
        float a = clfb[lane];
#pragma unroll
        for (int j = 0; j < DIM; j++) a = fmaf(ms[j], clfW[j*NC + lane], a);
        out_logits[((size_t)b*NK + k)*NC + lane] = a;
    }
}

// ---------------- launch ----------------
extern "C" void kernel_launch(void* const* d_in, const int* in_sizes, int n_in,
                              void* d_out, int out_size, void* d_ws, size_t ws_size,
                              hipStream_t stream)
{
    const float* x     = (const float*)d_in[0];
    const int*   ei    = (const int*)  d_in[1];
    const int*   batch = (const int*)  d_in[2];
    const float* ceW1 = (const float*)d_in[3];
    const float* ceb1 = (const float*)d_in[4];
    const float* ceW2 = (const float*)d_in[5];
    const float* ceb2 = (const float*)d_in[6];
    const float* ceeps= (const float*)d_in[7];
    const float* clW1 = (const float*)d_in[8];
    const float* clb1 = (const float*)d_in[9];
    const float* clW2 = (const float*)d_in[10];
    const float* clb2 = (const float*)d_in[11];
    const float* cleps= (const float*)d_in[12];
    const float* nmW1 = (const float*)d_in[13];
    const float* nmb1 = (const float*)d_in[14];
    const float* nmW2 = (const float*)d_in[15];
    const float* nmb2 = (const float*)d_in[16];
    const float* emW1 = (const float*)d_in[17];
    const float* emb1 = (const float*)d_in[18];
    const float* emW2 = (const float*)d_in[19];
    const float* emb2 = (const float*)d_in[20];
    const float* fmW1 = (const float*)d_in[21];
    const float* fmb1 = (const float*)d_in[22];
    const float* fmW2 = (const float*)d_in[23];
    const float* fmb2 = (const float*)d_in[24];
    const float* clfW = (const float*)d_in[25];
    const float* clfb = (const float*)d_in[26];

    // output layout (f32, flat, return order)
    float* out        = (float*)d_out;
    float* out_logits = out;                       // [B,K,C]
    float* out_hst    = out + 10240;               // [B,K,H]
    float* out_horig  = out + 75776;               // [B,H]
    float* nm_out     = out + 92160;               // [N,K]
    float* em_out     = out + 292160;              // [E,K]
    float* fm_out     = out + 3492160;             // [N,K,F]

    // workspace layout
    int* rowptr  = (int*)d_ws;                     // N+1
    int* cursor  = rowptr + (N_NODES + 1);         // N
    int* deg     = cursor + N_NODES;               // N
    int* csr_src = deg + N_NODES;                  // E
    int* csr_eid = csr_src + N_EDGES;              // E
    int* bsum    = csr_eid + N_EDGES;              // 256
    int* boff    = bsum + 256;                     // 256
    size_t int_count = (size_t)(N_NODES+1) + N_NODES + N_NODES + N_EDGES + N_EDGES + 512;
    int_count = (int_count + 3) & ~(size_t)3;
    float* tbuf = (float*)(((int*)d_ws) + int_count);       // N*64 f32 (agg output)
    const size_t ND = (size_t)N_NODES*DIM;
    ushort_* hxs = (ushort_*)(tbuf + ND);                   // N*64 bf16 (x / h0 / CL ping)
    ushort_* TA  = hxs + ND;                                // N*64 bf16 (Z lives here)
    ushort_* TB  = TA + ND;                                 // N*64 bf16
    ushort_* pt4 = TB + ND;                                 // N*256 bf16
    ushort_* pb4 = pt4 + ND*NK;                             // N*256 bf16
    ushort_* ewc = pb4 + ND*NK;                             // 4*E bf16

    const int GT = (N_NODES + 63) / 64;     // 782 tiles
    const int GW = (N_NODES + 3) / 4;       // wave-per-node blocks

    // ---- CSR build ----
    hipMemsetAsync(deg, 0, N_NODES*sizeof(int), stream);
    deg_hist_kernel<<<(N_EDGES+255)/256, 256, 0, stream>>>(ei, deg);
    scan_p1<<<SCAN_BLKS, 256, 0, stream>>>(deg, rowptr, bsum);
    scan_p2<<<1, 256, 0, stream>>>(bsum, boff);
    scan_p3<<<SCAN_BLKS, 256, 0, stream>>>(rowptr, boff, cursor);
    csr_fill_kernel<<<(N_EDGES+255)/256, 256, 0, stream>>>(ei, cursor, csr_src, csr_eid);

    // ---- x -> bf16 ----
    tobf16_kernel<<<(N_NODES*DIM/4+255)/256, 256, 0, stream>>>(x, hxs);

    // ---- causal encoder GIN (3 layers): hxs -> TA -> TB -> TA (Z16 = TA) ----
    agg16_kernel<false><<<GW, 256, 0, stream>>>(hxs, tbuf, rowptr, csr_src, nullptr, ceeps + 0);
    mlp2_kernel<0,0,1><<<GT, 256, 0, stream>>>(tbuf, TA, ceW1 + 0*DIM*DIM, ceb1 + 0*DIM,
                                               ceW2 + 0*DIM*DIM, ceb2 + 0*DIM, DIM, 0);
    agg16_kernel<false><<<GW, 256, 0, stream>>>(TA, tbuf, rowptr, csr_src, nullptr, ceeps + 1);
    mlp2_kernel<0,0,1><<<GT, 256, 0, stream>>>(tbuf, TB, ceW1 + 1*DIM*DIM, ceb1 + 1*DIM,
                                               ceW2 + 1*DIM*DIM, ceb2 + 1*DIM, DIM, 0);
    agg16_kernel<false><<<GW, 256, 0, stream>>>(TB, tbuf, rowptr, csr_src, nullptr, ceeps + 2);
    mlp2_kernel<0,0,1><<<GT, 256, 0, stream>>>(tbuf, TA, ceW1 + 2*DIM*DIM, ceb1 + 2*DIM,
                                               ceW2 + 2*DIM*DIM, ceb2 + 2*DIM, DIM, 0);
    const ushort_* Z16 = TA;

    // ---- h_orig pooling ----
    pool_orig_kernel<<<NB, 64, 0, stream>>>(Z16, batch, out_horig);

    // ---- edge mask projections (all k) + fused edge mask ----
    em_proj4_kernel<<<dim3(GT, 2*NK), 256, 0, stream>>>(Z16, emW1, pt4, pb4);
    edge_mask16_kernel<<<GW, 256, 0, stream>>>(pt4, pb4, rowptr, csr_src, csr_eid,
                                               emb1, emW2, emb2, em_out, ewc);

    // ---- per-expert ----
    for (int k = 0; k < NK; ++k){
        nm_kernel<<<GT, 256, 0, stream>>>(Z16, nm_out, nmW1 + (size_t)k*DIM*DIM, nmb1 + k*DIM,
                                          nmW2 + k*DIM, nmb2 + k, k);
        mlp2_kernel<1,1,0><<<GT, 256, 0, stream>>>(Z16, fm_out, fmW1 + (size_t)k*DIM*DIM, fmb1 + k*DIM,
                                                   fmW2 + (size_t)k*DIM*DIM, fmb2 + k*DIM,
                                                   (long)NK*DIM, (long)k*DIM);
        build_h0_kernel<<<(N_NODES*16+255)/256, 256, 0, stream>>>(x, nm_out, fm_out, hxs, k);
        const ushort_* ew_k = ewc + (size_t)k*N_EDGES;
        agg16_kernel<true><<<GW, 256, 0, stream>>>(hxs, tbuf, rowptr, csr_src, ew_k, cleps + 0);
        mlp2_kernel<0,0,1><<<GT, 256, 0, stream>>>(tbuf, TB, clW1 + 0*DIM*DIM, clb1 + 0*DIM,
                                                   clW2 + 0*DIM*DIM, clb2 + 0*DIM, DIM, 0);
        agg16_kernel<true><<<GW, 256, 0, stream>>>(TB, tbuf, rowptr, csr_src, ew_k, cleps + 1);
        mlp2_kernel<0,0,1><<<GT, 256, 0, stream>>>(tbuf, hxs, clW1 + 1*DIM*DIM, clb1 + 1*DIM,
                                                   clW2 + 1*DIM*DIM, clb2 + 1*DIM, DIM, 0);
        agg16_kernel<true><<<GW, 256, 0, stream>>>(hxs, tbuf, rowptr, csr_src, ew_k, cleps + 2);
        mlp2_kernel<0,0,1><<<GT, 256, 0, stream>>>(tbuf, TB, clW1 + 2*DIM*DIM, clb1 + 2*DIM,
                                                   clW2 + 2*DIM*DIM, clb2 + 2*DIM, DIM, 0);
        pool_expert_kernel<<<NB, 64, 0, stream>>>(TB, batch, clfW + (size_t)k*DIM*NC, clfb + k*NC,
                                                  out_logits, out_hst, k);
    }
}

// Round 6
// 995.387 us; speedup vs baseline: 2.8085x; 1.4161x over previous
//
#include <hip/hip_runtime.h>
#include <math.h>

#define N_NODES 50000
#define N_EDGES 800000
#define DIM 64
#define NB 256
#define NK 4
#define NC 10
#define TPAD 68
#define SCAN_BLKS 196  // ceil(50000/256)

typedef unsigned int uint_;
typedef unsigned short ushort_;

__device__ __forceinline__ float sigmoidf_(float x){ return 1.f/(1.f+__expf(-x)); }
__device__ __forceinline__ float bf2f(ushort_ v){ return __uint_as_float(((uint_)v)<<16); }
__device__ __forceinline__ float bflo(uint_ u){ return __uint_as_float(u<<16); }
__device__ __forceinline__ float bfhi(uint_ u){ return __uint_as_float(u & 0xFFFF0000u); }
__device__ __forceinline__ ushort_ f2bf(float f){
    uint_ u = __float_as_uint(f);
    u = (u + 0x7FFFu + ((u>>16)&1u)) >> 16;
    return (ushort_)u;
}

// ---------------- CSR build ----------------
__global__ void deg_hist_kernel(const int* __restrict__ ei, int* __restrict__ deg){
    int e = blockIdx.x*256 + threadIdx.x;
    if (e < N_EDGES) atomicAdd(&deg[ei[N_EDGES + e]], 1);
}

__global__ __launch_bounds__(256)
void scan_p1(const int* __restrict__ deg, int* __restrict__ rowptr, int* __restrict__ bsum){
    __shared__ int s[256];
    int tid = threadIdx.x;
    int i = blockIdx.x*256 + tid;
    int v = (i < N_NODES) ? deg[i] : 0;
    s[tid] = v;
    __syncthreads();
    for (int off = 1; off < 256; off <<= 1){
        int t = (tid >= off) ? s[tid - off] : 0;
        __syncthreads();
        s[tid] += t;
        __syncthreads();
    }
    if (i < N_NODES) rowptr[i] = s[tid] - v;
    if (tid == 255) bsum[blockIdx.x] = s[255];
}

__global__ __launch_bounds__(256)
void scan_p2(const int* __restrict__ bsum, int* __restrict__ boff){
    __shared__ int s[256];
    int tid = threadIdx.x;
    int v = (tid < SCAN_BLKS) ? bsum[tid] : 0;
    s[tid] = v;
    __syncthreads();
    for (int off = 1; off < 256; off <<= 1){
        int t = (tid >= off) ? s[tid - off] : 0;
        __syncthreads();
        s[tid] += t;
        __syncthreads();
    }
    boff[tid] = s[tid] - v;
}

__global__ __launch_bounds__(256)
void scan_p3(int* __restrict__ rowptr, const int* __restrict__ boff, int* __restrict__ cursor){
    int i = blockIdx.x*256 + threadIdx.x;
    if (i < N_NODES){
        int r = rowptr[i] + boff[blockIdx.x];
        rowptr[i] = r;
        cursor[i] = r;
    }
    if (i == 0) rowptr[N_NODES] = N_EDGES;
}

__global__ void csr_fill_kernel(const int* __restrict__ ei, int* __restrict__ cursor,
                                int* __restrict__ csr_src, int* __restrict__ csr_eid){
    int e = blockIdx.x*256 + threadIdx.x;
    if (e < N_EDGES){
        int d = ei[N_EDGES + e];
        int pos = atomicAdd(&cursor[d], 1);
        csr_src[pos] = ei[e];
        csr_eid[pos] = e;
    }
}

// ---------------- f32 -> bf16 copy ----------------
__global__ void tobf16_kernel(const float* __restrict__ x, ushort_* __restrict__ o){
    int i = blockIdx.x*256 + threadIdx.x;
    if (i < N_NODES*DIM/4){
        float4 v = *(const float4*)&x[(size_t)i*4];
        ushort4 o4;
        o4.x = f2bf(v.x); o4.y = f2bf(v.y); o4.z = f2bf(v.z); o4.w = f2bf(v.w);
        *(ushort4*)&o[(size_t)i*4] = o4;
    }
}

// ---------------- CE aggregation: 2 feats/lane, 2 edges per half-wave, no ew ----------------
__global__ __launch_bounds__(256)
void agg_ce_kernel(const ushort_* __restrict__ hin, float* __restrict__ outt,
                   const int* __restrict__ rowptr, const int* __restrict__ csr_src,
                   const float* __restrict__ eps_p)
{
    const int n = blockIdx.x*4 + (threadIdx.x >> 6);
    if (n >= N_NODES) return;
    const int lane = threadIdx.x & 63;
    const int f2 = lane & 31;   // feature pair
    const int p  = lane >> 5;   // edge-group parity
    float a0 = 0.f, a1 = 0.f;
    int idx = rowptr[n];
    const int end = rowptr[n+1];
    for (; idx + 4 <= end; idx += 4){
        int e0 = idx + p*2, e1 = e0 + 1;
        int s0 = csr_src[e0], s1 = csr_src[e1];
        uint_ g0 = *(const uint_*)&hin[(size_t)s0*DIM + f2*2];
        uint_ g1 = *(const uint_*)&hin[(size_t)s1*DIM + f2*2];
        a0 += bflo(g0) + bflo(g1);
        a1 += bfhi(g0) + bfhi(g1);
    }
    for (; idx < end; idx += 2){
        int e = idx + p;
        bool v = e < end;
        int s = v ? csr_src[e] : 0;
        uint_ g = v ? *(const uint_*)&hin[(size_t)s*DIM + f2*2] : 0u;
        a0 += bflo(g);
        a1 += bfhi(g);
    }
    a0 += __shfl_xor(a0, 32);
    a1 += __shfl_xor(a1, 32);
    const float epv = 1.0f + *eps_p;
    uint_ hs = *(const uint_*)&hin[(size_t)n*DIM + f2*2];
    a0 = fmaf(epv, bflo(hs), a0);
    a1 = fmaf(epv, bfhi(hs), a1);
    if (p == 0){
        *(float2*)&outt[(size_t)n*DIM + f2*2] = make_float2(a0, a1);
    }
}

// ---------------- fused 4-expert CL aggregation over interleaved tables ----------------
// h4: [n][k*64+f] bf16 (512B row). lane covers (k=lane>>4, 4 feats). ewi: [i*4+k] bf16.
// Output bf16 (t16) to keep workspace <= ~96MB.
__global__ __launch_bounds__(256)
void agg4_kernel(const ushort_* __restrict__ h4, ushort_* __restrict__ out4,
                 const int* __restrict__ rowptr, const int* __restrict__ csr_src,
                 const ushort_* __restrict__ ewi, const float* __restrict__ eps_p)
{
    const int n = blockIdx.x*4 + (threadIdx.x >> 6);
    if (n >= N_NODES) return;
    const int lane = threadIdx.x & 63;
    const int k = lane >> 4;
    const float epv = 1.0f + *eps_p;
    uint2 self = *(const uint2*)&h4[(size_t)n*(NK*DIM) + lane*4];
    float c0 = epv*bflo(self.x), c1 = epv*bfhi(self.x);
    float c2 = epv*bflo(self.y), c3 = epv*bfhi(self.y);
    int idx = rowptr[n];
    const int end = rowptr[n+1];
    for (; idx + 4 <= end; idx += 4){
        int s0 = csr_src[idx+0], s1 = csr_src[idx+1];
        int s2 = csr_src[idx+2], s3 = csr_src[idx+3];
        uint2 g0 = *(const uint2*)&h4[(size_t)s0*(NK*DIM) + lane*4];
        uint2 g1 = *(const uint2*)&h4[(size_t)s1*(NK*DIM) + lane*4];
        uint2 g2 = *(const uint2*)&h4[(size_t)s2*(NK*DIM) + lane*4];
        uint2 g3 = *(const uint2*)&h4[(size_t)s3*(NK*DIM) + lane*4];
        float w0 = bf2f(ewi[(size_t)(idx+0)*NK + k]);
        float w1 = bf2f(ewi[(size_t)(idx+1)*NK + k]);
        float w2 = bf2f(ewi[(size_t)(idx+2)*NK + k]);
        float w3 = bf2f(ewi[(size_t)(idx+3)*NK + k]);
        c0 = fmaf(w0, bflo(g0.x), c0); c1 = fmaf(w0, bfhi(g0.x), c1);
        c2 = fmaf(w0, bflo(g0.y), c2); c3 = fmaf(w0, bfhi(g0.y), c3);
        c0 = fmaf(w1, bflo(g1.x), c0); c1 = fmaf(w1, bfhi(g1.x), c1);
        c2 = fmaf(w1, bflo(g1.y), c2); c3 = fmaf(w1, bfhi(g1.y), c3);
        c0 = fmaf(w2, bflo(g2.x), c0); c1 = fmaf(w2, bfhi(g2.x), c1);
        c2 = fmaf(w2, bflo(g2.y), c2); c3 = fmaf(w2, bfhi(g2.y), c3);
        c0 = fmaf(w3, bflo(g3.x), c0); c1 = fmaf(w3, bfhi(g3.x), c1);
        c2 = fmaf(w3, bflo(g3.y), c2); c3 = fmaf(w3, bfhi(g3.y), c3);
    }
    for (; idx < end; ++idx){
        int s = csr_src[idx];
        uint2 g = *(const uint2*)&h4[(size_t)s*(NK*DIM) + lane*4];
        float w = bf2f(ewi[(size_t)idx*NK + k]);
        c0 = fmaf(w, bflo(g.x), c0); c1 = fmaf(w, bfhi(g.x), c1);
        c2 = fmaf(w, bflo(g.y), c2); c3 = fmaf(w, bfhi(g.y), c3);
    }
    ushort4 o;
    o.x = f2bf(c0); o.y = f2bf(c1); o.z = f2bf(c2); o.w = f2bf(c3);
    *(ushort4*)&out4[(size_t)n*(NK*DIM) + lane*4] = o;
}

// ---------------- LDS staging helpers (256 threads) ----------------
__device__ __forceinline__ void load_tileT_f32s(const float* __restrict__ in, float As[DIM][TPAD],
                                                int m0, int tid, int istride, int ibase){
    int r = tid >> 2, cq = (tid & 3) * 16;
    bool valid = (m0 + r) < N_NODES;
#pragma unroll
    for (int i = 0; i < 4; i++){
        float4 v = valid ? *(const float4*)&in[(size_t)(m0 + r)*istride + ibase + cq + 4*i]
                         : make_float4(0.f, 0.f, 0.f, 0.f);
        As[cq + 4*i + 0][r] = v.x;
        As[cq + 4*i + 1][r] = v.y;
        As[cq + 4*i + 2][r] = v.z;
        As[cq + 4*i + 3][r] = v.w;
    }
}

__device__ __forceinline__ void load_tileT_b16s(const ushort_* __restrict__ in, float As[DIM][TPAD],
                                                int m0, int tid, int istride, int ibase){
    int r = tid >> 2, cq = (tid & 3) * 16;
    bool valid = (m0 + r) < N_NODES;
    uint_ us[8] = {0,0,0,0,0,0,0,0};
    if (valid){
        const uint_* p = (const uint_*)&in[(size_t)(m0 + r)*istride + ibase + cq];
        uint4 a = *(const uint4*)p;
        uint4 b = *(const uint4*)(p + 4);
        us[0]=a.x; us[1]=a.y; us[2]=a.z; us[3]=a.w;
        us[4]=b.x; us[5]=b.y; us[6]=b.z; us[7]=b.w;
    }
#pragma unroll
    for (int w = 0; w < 8; w++){
        As[cq + 2*w + 0][r] = bflo(us[w]);
        As[cq + 2*w + 1][r] = bfhi(us[w]);
    }
}

__device__ __forceinline__ void load_w(const float* __restrict__ W, float Ws[DIM][TPAD], int tid){
    int kr = tid >> 2, cq = (tid & 3) * 16;
#pragma unroll
    for (int i = 0; i < 4; i++){
        *(float4*)&Ws[kr][cq + 4*i] = *(const float4*)&W[(size_t)kr*DIM + cq + 4*i];
    }
}

// ---------------- flexible fused 2-layer MLP over a 64-node tile ----------------
// grid.y = k (expert). IN16: bf16 input. ACT2: 0=relu 1=sigmoid. OUT16: bf16 output.
// PERK_W: weights indexed by k. istride/ostride in elements; ibase=k*ibase_k, obase=k*obase_k.
template<int IN16, int ACT2, int OUT16, int PERK_W>
__global__ __launch_bounds__(256)
void mlpX_kernel(const void* __restrict__ inp, void* __restrict__ outp,
                 const float* __restrict__ W1, const float* __restrict__ b1,
                 const float* __restrict__ W2, const float* __restrict__ b2,
                 int istride, int ibase_k, int ostride, int obase_k)
{
    __shared__ __align__(16) float As[DIM][TPAD];
    __shared__ __align__(16) float Ws[DIM][TPAD];
    __shared__ __align__(16) float Ts[DIM][TPAD];
    const int tid = threadIdx.x;
    const int tx = tid & 15, ty = tid >> 4;
    const int m0 = blockIdx.x * 64;
    const int k = blockIdx.y;
    if (PERK_W){
        W1 += (size_t)k*DIM*DIM; b1 += (size_t)k*DIM;
        W2 += (size_t)k*DIM*DIM; b2 += (size_t)k*DIM;
    }
    const int ibase = k * ibase_k;
    const size_t obase = (size_t)k * obase_k;

    if (IN16) load_tileT_b16s((const ushort_*)inp, As, m0, tid, istride, ibase);
    else      load_tileT_f32s((const float*)inp, As, m0, tid, istride, ibase);
    load_w(W1, Ws, tid);
    __syncthreads();

    float acc[4][4];
    {
        float4 b1v = *(const float4*)&b1[tx*4];
        float bv[4] = {b1v.x, b1v.y, b1v.z, b1v.w};
#pragma unroll
        for (int i = 0; i < 4; i++)
#pragma unroll
            for (int j = 0; j < 4; j++) acc[i][j] = bv[j];
    }
#pragma unroll 8
    for (int kk = 0; kk < DIM; kk++){
        float4 a = *(const float4*)&As[kk][ty*4];
        float4 w = *(const float4*)&Ws[kk][tx*4];
        float av[4] = {a.x, a.y, a.z, a.w};
        float wv[4] = {w.x, w.y, w.z, w.w};
#pragma unroll
        for (int i = 0; i < 4; i++)
#pragma unroll
            for (int j = 0; j < 4; j++) acc[i][j] = fmaf(av[i], wv[j], acc[i][j]);
    }
#pragma unroll
    for (int j = 0; j < 4; j++){
        float4 v = make_float4(fmaxf(acc[0][j],0.f), fmaxf(acc[1][j],0.f),
                               fmaxf(acc[2][j],0.f), fmaxf(acc[3][j],0.f));
        *(float4*)&Ts[tx*4 + j][ty*4] = v;
    }
    __syncthreads();
    load_w(W2, Ws, tid);
    __syncthreads();

    float acc2[4][4];
    {
        float4 b2v = *(const float4*)&b2[tx*4];
        float bv[4] = {b2v.x, b2v.y, b2v.z, b2v.w};
#pragma unroll
        for (int i = 0; i < 4; i++)
#pragma unroll
            for (int j = 0; j < 4; j++) acc2[i][j] = bv[j];
    }
#pragma unroll 8
    for (int kk = 0; kk < DIM; kk++){
        float4 a = *(const float4*)&Ts[kk][ty*4];
        float4 w = *(const float4*)&Ws[kk][tx*4];
        float av[4] = {a.x, a.y, a.z, a.w};
        float wv[4] = {w.x, w.y, w.z, w.w};
#pragma unroll
        for (int i = 0; i < 4; i++)
#pragma unroll
            for (int j = 0; j < 4; j++) acc2[i][j] = fmaf(av[i], wv[j], acc2[i][j]);
    }
#pragma unroll
    for (int i = 0; i < 4; i++){
        int m = m0 + ty*4 + i;
        if (m < N_NODES){
            float v0, v1, v2, v3;
            if (ACT2 == 0){
                v0 = fmaxf(acc2[i][0],0.f); v1 = fmaxf(acc2[i][1],0.f);
                v2 = fmaxf(acc2[i][2],0.f); v3 = fmaxf(acc2[i][3],0.f);
            } else {
                v0 = sigmoidf_(acc2[i][0]); v1 = sigmoidf_(acc2[i][1]);
                v2 = sigmoidf_(acc2[i][2]); v3 = sigmoidf_(acc2[i][3]);
            }
            if (OUT16){
                ushort4 o;
                o.x = f2bf(v0); o.y = f2bf(v1); o.z = f2bf(v2); o.w = f2bf(v3);
                *(ushort4*)&((ushort_*)outp)[obase + (size_t)m*ostride + tx*4] = o;
            } else {
                *(float4*)&((float*)outp)[obase + (size_t)m*ostride + tx*4] =
                    make_float4(v0, v1, v2, v3);
            }
        }
    }
}

// ---------------- node-mask (all experts via grid.y) ----------------
__global__ __launch_bounds__(256)
void nm4_kernel(const ushort_* __restrict__ Z16, float* __restrict__ nm_out,
                const float* __restrict__ nmW1, const float* __restrict__ nmb1,
                const float* __restrict__ nmW2, const float* __restrict__ nmb2)
{
    __shared__ __align__(16) float As[DIM][TPAD];
    __shared__ __align__(16) float Ws[DIM][TPAD];
    __shared__ __align__(16) float Ts[DIM][TPAD];
    __shared__ float w2s[DIM];
    __shared__ float red[4][DIM];
    const int tid = threadIdx.x;
    const int tx = tid & 15, ty = tid >> 4;
    const int m0 = blockIdx.x * 64;
    const int k = blockIdx.y;
    const float* W1 = nmW1 + (size_t)k*DIM*DIM;
    const float* b1 = nmb1 + (size_t)k*DIM;
    const float* w2 = nmW2 + (size_t)k*DIM;

    load_tileT_b16s(Z16, As, m0, tid, DIM, 0);
    load_w(W1, Ws, tid);
    if (tid < DIM) w2s[tid] = w2[tid];
    __syncthreads();

    float acc[4][4];
    {
        float4 b1v = *(const float4*)&b1[tx*4];
        float bv[4] = {b1v.x, b1v.y, b1v.z, b1v.w};
#pragma unroll
        for (int i = 0; i < 4; i++)
#pragma unroll
            for (int j = 0; j < 4; j++) acc[i][j] = bv[j];
    }
#pragma unroll 8
    for (int kk = 0; kk < DIM; kk++){
        float4 a = *(const float4*)&As[kk][ty*4];
        float4 w = *(const float4*)&Ws[kk][tx*4];
        float av[4] = {a.x, a.y, a.z, a.w};
        float wv[4] = {w.x, w.y, w.z, w.w};
#pragma unroll
        for (int i = 0; i < 4; i++)
#pragma unroll
            for (int j = 0; j < 4; j++) acc[i][j] = fmaf(av[i], wv[j], acc[i][j]);
    }
#pragma unroll
    for (int j = 0; j < 4; j++){
        float4 v = make_float4(fmaxf(acc[0][j],0.f), fmaxf(acc[1][j],0.f),
                               fmaxf(acc[2][j],0.f), fmaxf(acc[3][j],0.f));
        *(float4*)&Ts[tx*4 + j][ty*4] = v;
    }
    __syncthreads();
    {
        int m = tid & 63, q = tid >> 6;
        float p = 0.f;
#pragma unroll
        for (int kk = 0; kk < 16; kk++) p = fmaf(Ts[q*16 + kk][m], w2s[q*16 + kk], p);
        red[q][m] = p;
    }
    __syncthreads();
    if (tid < DIM){
        int m = m0 + tid;
        if (m < N_NODES){
            float sm = red[0][tid] + red[1][tid] + red[2][tid] + red[3][tid] + nmb2[k];
            nm_out[(size_t)m*NK + k] = sigmoidf_(sm);
        }
    }
}

// ---------------- edge-mask projections for ALL experts: grid (tiles, 8) ----------------
__global__ __launch_bounds__(256)
void em_proj4_kernel(const ushort_* __restrict__ Z16, const float* __restrict__ emW1,
                     ushort_* __restrict__ pt4, ushort_* __restrict__ pb4)
{
    __shared__ __align__(16) float As[DIM][TPAD];
    __shared__ __align__(16) float Ws[DIM][TPAD];
    const int s = blockIdx.y;
    const int k = s >> 1, side = s & 1;
    const float* W = emW1 + ((size_t)k*2 + side)*DIM*DIM;
    ushort_* outp = side ? pb4 : pt4;
    const int tid = threadIdx.x;
    const int tx = tid & 15, ty = tid >> 4;
    const int m0 = blockIdx.x * 64;

    load_tileT_b16s(Z16, As, m0, tid, DIM, 0);
    load_w(W, Ws, tid);
    __syncthreads();

    float acc[4][4] = {};
#pragma unroll 8
    for (int kk = 0; kk < DIM; kk++){
        float4 a = *(const float4*)&As[kk][ty*4];
        float4 w = *(const float4*)&Ws[kk][tx*4];
        float av[4] = {a.x, a.y, a.z, a.w};
        float wv[4] = {w.x, w.y, w.z, w.w};
#pragma unroll
        for (int i = 0; i < 4; i++)
#pragma unroll
            for (int j = 0; j < 4; j++) acc[i][j] = fmaf(av[i], wv[j], acc[i][j]);
    }
#pragma unroll
    for (int i = 0; i < 4; i++){
        int m = m0 + ty*4 + i;
        if (m < N_NODES){
            ushort4 o;
            o.x = f2bf(acc[i][0]); o.y = f2bf(acc[i][1]);
            o.z = f2bf(acc[i][2]); o.w = f2bf(acc[i][3]);
            *(ushort4*)&outp[(size_t)m*(NK*DIM) + k*DIM + tx*4] = o;
        }
    }
}

// ---------------- edge mask, all 4 experts, wave-per-node over CSR ----------------
__global__ __launch_bounds__(256)
void edge_mask16_kernel(const ushort_* __restrict__ pt4, const ushort_* __restrict__ pb4,
                        const int* __restrict__ rowptr, const int* __restrict__ csr_src,
                        const int* __restrict__ csr_eid,
                        const float* __restrict__ emb1, const float* __restrict__ emW2,
                        const float* __restrict__ emb2,
                        float* __restrict__ em_out, ushort_* __restrict__ ewi)
{
    const int n = blockIdx.x*4 + (threadIdx.x >> 6);
    if (n >= N_NODES) return;
    const int lane = threadIdx.x & 63;
    const int k = lane >> 4, fq = lane & 15;
    const float4 w2v = *(const float4*)&emW2[k*DIM + fq*4];
    const float4 b1v = *(const float4*)&emb1[k*DIM + fq*4];
    const float b2 = emb2[k];
    uint2 pbu = *(const uint2*)&pb4[(size_t)n*(NK*DIM) + k*DIM + fq*4];
    const float pre0 = bflo(pbu.x) + b1v.x;
    const float pre1 = bfhi(pbu.x) + b1v.y;
    const float pre2 = bflo(pbu.y) + b1v.z;
    const float pre3 = bfhi(pbu.y) + b1v.w;
    int i = rowptr[n];
    const int end = rowptr[n+1];
    for (; i + 2 <= end; i += 2){
        int s0 = csr_src[i], s1 = csr_src[i+1];
        uint2 a0 = *(const uint2*)&pt4[(size_t)s0*(NK*DIM) + k*DIM + fq*4];
        uint2 a1 = *(const uint2*)&pt4[(size_t)s1*(NK*DIM) + k*DIM + fq*4];
        float p0 = fmaxf(bflo(a0.x) + pre0, 0.f)*w2v.x + fmaxf(bfhi(a0.x) + pre1, 0.f)*w2v.y
                 + fmaxf(bflo(a0.y) + pre2, 0.f)*w2v.z + fmaxf(bfhi(a0.y) + pre3, 0.f)*w2v.w;
        float p1 = fmaxf(bflo(a1.x) + pre0, 0.f)*w2v.x + fmaxf(bfhi(a1.x) + pre1, 0.f)*w2v.y
                 + fmaxf(bflo(a1.y) + pre2, 0.f)*w2v.z + fmaxf(bfhi(a1.y) + pre3, 0.f)*w2v.w;
        p0 += __shfl_xor(p0, 1, 16); p1 += __shfl_xor(p1, 1, 16);
        p0 += __shfl_xor(p0, 2, 16); p1 += __shfl_xor(p1, 2, 16);
        p0 += __shfl_xor(p0, 4, 16); p1 += __shfl_xor(p1, 4, 16);
        p0 += __shfl_xor(p0, 8, 16); p1 += __shfl_xor(p1, 8, 16);
        if (fq == 0){
            float m0v = sigmoidf_(p0 + b2);
            float m1v = sigmoidf_(p1 + b2);
            em_out[(size_t)csr_eid[i]*NK + k]   = m0v;
            em_out[(size_t)csr_eid[i+1]*NK + k] = m1v;
            ewi[(size_t)i*NK + k]     = f2bf(m0v);
            ewi[(size_t)(i+1)*NK + k] = f2bf(m1v);
        }
    }
    for (; i < end; ++i){
        int s0 = csr_src[i];
        uint2 a0 = *(const uint2*)&pt4[(size_t)s0*(NK*DIM) + k*DIM + fq*4];
        float p0 = fmaxf(bflo(a0.x) + pre0, 0.f)*w2v.x + fmaxf(bfhi(a0.x) + pre1, 0.f)*w2v.y
                 + fmaxf(bflo(a0.y) + pre2, 0.f)*w2v.z + fmaxf(bfhi(a0.y) + pre3, 0.f)*w2v.w;
        p0 += __shfl_xor(p0, 1, 16);
        p0 += __shfl_xor(p0, 2, 16);
        p0 += __shfl_xor(p0, 4, 16);
        p0 += __shfl_xor(p0, 8, 16);
        if (fq == 0){
            float m0v = sigmoidf_(p0 + b2);
            em_out[(size_t)csr_eid[i]*NK + k] = m0v;
            ewi[(size_t)i*NK + k] = f2bf(m0v);
        }
    }
}

// ---------------- masked_x for all experts -> interleaved h4 ----------------
__global__ void build_h04_kernel(const float* __restrict__ x, const float* __restrict__ nm_out,
                                 const float* __restrict__ fm_out, ushort_* __restrict__ h4)
{
    int t = blockIdx.x*256 + threadIdx.x;
    if (t < N_NODES*64){
        int n = t >> 6;
        int q = t & 63;           // q = k*16 + c4
        int k = q >> 4, c = (q & 15) * 4;
        float nm = nm_out[(size_t)n*NK + k];
        float4 xv = *(const float4*)&x[(size_t)n*DIM + c];
        float4 fv = *(const float4*)&fm_out[((size_t)n*NK + k)*DIM + c];
        ushort4 o;
        o.x = f2bf(xv.x*nm*fv.x); o.y = f2bf(xv.y*nm*fv.y);
        o.z = f2bf(xv.z*nm*fv.z); o.w = f2bf(xv.w*nm*fv.w);
        *(ushort4*)&h4[(size_t)n*(NK*DIM) + k*DIM + c] = o;
    }
}

// ---------------- pooling ----------------
__device__ __forceinline__ int lower_bound_(const int* a, int n, int v){
    int lo = 0, hi = n;
    while (lo < hi){ int m = (lo + hi) >> 1; if (a[m] < v) lo = m + 1; else hi = m; }
    return lo;
}

__global__ __launch_bounds__(64)
void pool_orig_kernel(const ushort_* __restrict__ h, const int* __restrict__ batch, float* __restrict__ out){
    int b = blockIdx.x, lane = threadIdx.x;
    int lo = lower_bound_(batch, N_NODES, b);
    int hi = lower_bound_(batch, N_NODES, b+1);
    float s = 0.f;
    int n = lo;
    for (; n + 4 <= hi; n += 4){
        s += bf2f(h[(size_t)n*DIM + lane]) + bf2f(h[(size_t)(n+1)*DIM + lane])
           + bf2f(h[(size_t)(n+2)*DIM + lane]) + bf2f(h[(size_t)(n+3)*DIM + lane]);
    }
    for (; n < hi; ++n) s += bf2f(h[(size_t)n*DIM + lane]);
    out[(size_t)b*DIM + lane] = s / fmaxf((float)(hi - lo), 1.f);
}

__global__ __launch_bounds__(64)
void pool4_kernel(const ushort_* __restrict__ h4, const int* __restrict__ batch,
                  const float* __restrict__ clfW, const float* __restrict__ clfb,
                  float* __restrict__ out_logits, float* __restrict__ out_hst)
{
    __shared__ float ms[DIM];
    int b = blockIdx.x, k = blockIdx.y, lane = threadIdx.x;
    int lo = lower_bound_(batch, N_NODES, b);
    int hi = lower_bound_(batch, N_NODES, b+1);
    const ushort_* h = h4 + (size_t)k*DIM;
    float s = 0.f;
    int n = lo;
    for (; n + 4 <= hi; n += 4){
        s += bf2f(h[(size_t)n*(NK*DIM) + lane]) + bf2f(h[(size_t)(n+1)*(NK*DIM) + lane])
           + bf2f(h[(size_t)(n+2)*(NK*DIM) + lane]) + bf2f(h[(size_t)(n+3)*(NK*DIM) + lane]);
    }
    for (; n < hi; ++n) s += bf2f(h[(size_t)n*(NK*DIM) + lane]);
    float m = s / fmaxf((float)(hi - lo), 1.f);
    out_hst[((size_t)b*NK + k)*DIM + lane] = m;
    ms[lane] = m;
    __syncthreads();
    if (lane < NC){
        float a = clfb[(size_t)k*NC + lane];
        const float* W = clfW + (size_t)k*DIM*NC;
#pragma unroll
        for (int j = 0; j < DIM; j++) a = fmaf(ms[j], W[j*NC + lane], a);
        out_logits[((size_t)b*NK + k)*NC + lane] = a;
    }
}

// ---------------- launch ----------------
extern "C" void kernel_launch(void* const* d_in, const int* in_sizes, int n_in,
                              void* d_out, int out_size, void* d_ws, size_t ws_size,
                              hipStream_t stream)
{
    const float* x     = (const float*)d_in[0];
    const int*   ei    = (const int*)  d_in[1];
    const int*   batch = (const int*)  d_in[2];
    const float* ceW1 = (const float*)d_in[3];
    const float* ceb1 = (const float*)d_in[4];
    const float* ceW2 = (const float*)d_in[5];
    const float* ceb2 = (const float*)d_in[6];
    const float* ceeps= (const float*)d_in[7];
    const float* clW1 = (const float*)d_in[8];
    const float* clb1 = (const float*)d_in[9];
    const float* clW2 = (const float*)d_in[10];
    const float* clb2 = (const float*)d_in[11];
    const float* cleps= (const float*)d_in[12];
    const float* nmW1 = (const float*)d_in[13];
    const float* nmb1 = (const float*)d_in[14];
    const float* nmW2 = (const float*)d_in[15];
    const float* nmb2 = (const float*)d_in[16];
    const float* emW1 = (const float*)d_in[17];
    const float* emb1 = (const float*)d_in[18];
    const float* emW2 = (const float*)d_in[19];
    const float* emb2 = (const float*)d_in[20];
    const float* fmW1 = (const float*)d_in[21];
    const float* fmb1 = (const float*)d_in[22];
    const float* fmW2 = (const float*)d_in[23];
    const float* fmb2 = (const float*)d_in[24];
    const float* clfW = (const float*)d_in[25];
    const float* clfb = (const float*)d_in[26];

    // output layout (f32, flat, return order)
    float* out        = (float*)d_out;
    float* out_logits = out;                       // [B,K,C]
    float* out_hst    = out + 10240;               // [B,K,H]
    float* out_horig  = out + 75776;               // [B,H]
    float* nm_out     = out + 92160;               // [N,K]
    float* em_out     = out + 292160;              // [E,K]
    float* fm_out     = out + 3492160;             // [N,K,F]

    // workspace layout (~96MB total, matches round-3 footprint)
    int* rowptr  = (int*)d_ws;                     // N+1
    int* cursor  = rowptr + (N_NODES + 1);         // N
    int* deg     = cursor + N_NODES;               // N
    int* csr_src = deg + N_NODES;                  // E
    int* csr_eid = csr_src + N_EDGES;              // E
    int* bsum    = csr_eid + N_EDGES;              // 256
    int* boff    = bsum + 256;                     // 256
    size_t int_count = (size_t)(N_NODES+1) + N_NODES + N_NODES + N_EDGES + N_EDGES + 512;
    int_count = (int_count + 3) & ~(size_t)3;
    const size_t ND = (size_t)N_NODES*DIM;
    // Region A (25.6MB): CE-phase {tbuf f32 (12.8), hx16 (6.4), TA (6.4)} ; CL-phase h4A
    float*   tbuf = (float*)(((int*)d_ws) + int_count);
    ushort_* hx16 = (ushort_*)(tbuf + ND);
    ushort_* TA   = hx16 + ND;                     // Z16 after CE
    ushort_* h4A  = (ushort_*)tbuf;                // N*256 bf16, overlays Region A exactly
    ushort_* TB   = TA + ND;                       // N*64 bf16
    ushort_* pt4  = TB + ND;                       // N*256 bf16 (25.6MB); CL-phase t16
    ushort_* pb4  = pt4 + ND*NK;                   // N*256 bf16 (25.6MB); CL-phase h4B
    ushort_* ewi  = pb4 + ND*NK;                   // E*4 bf16, edge-interleaved (6.4MB)
    ushort_* t16  = pt4;                           // agg4 output overlays dead pt4
    ushort_* h4B  = pb4;                           // overlays dead pb4

    const int GT = (N_NODES + 63) / 64;     // 782 tiles
    const int GW = (N_NODES + 3) / 4;       // wave-per-node blocks

    // ---- CSR build ----
    hipMemsetAsync(deg, 0, N_NODES*sizeof(int), stream);
    deg_hist_kernel<<<(N_EDGES+255)/256, 256, 0, stream>>>(ei, deg);
    scan_p1<<<SCAN_BLKS, 256, 0, stream>>>(deg, rowptr, bsum);
    scan_p2<<<1, 256, 0, stream>>>(bsum, boff);
    scan_p3<<<SCAN_BLKS, 256, 0, stream>>>(rowptr, boff, cursor);
    csr_fill_kernel<<<(N_EDGES+255)/256, 256, 0, stream>>>(ei, cursor, csr_src, csr_eid);

    // ---- x -> bf16 ----
    tobf16_kernel<<<(N_NODES*DIM/4+255)/256, 256, 0, stream>>>(x, hx16);

    // ---- causal encoder GIN (3 layers): hx16 -> TA -> TB -> TA (Z16 = TA) ----
    agg_ce_kernel<<<GW, 256, 0, stream>>>(hx16, tbuf, rowptr, csr_src, ceeps + 0);
    mlpX_kernel<0,0,1,0><<<dim3(GT,1), 256, 0, stream>>>(tbuf, TA, ceW1 + 0*DIM*DIM, ceb1 + 0*DIM,
                                                         ceW2 + 0*DIM*DIM, ceb2 + 0*DIM, DIM, 0, DIM, 0);
    agg_ce_kernel<<<GW, 256, 0, stream>>>(TA, tbuf, rowptr, csr_src, ceeps + 1);
    mlpX_kernel<0,0,1,0><<<dim3(GT,1), 256, 0, stream>>>(tbuf, TB, ceW1 + 1*DIM*DIM, ceb1 + 1*DIM,
                                                         ceW2 + 1*DIM*DIM, ceb2 + 1*DIM, DIM, 0, DIM, 0);
    agg_ce_kernel<<<GW, 256, 0, stream>>>(TB, tbuf, rowptr, csr_src, ceeps + 2);
    mlpX_kernel<0,0,1,0><<<dim3(GT,1), 256, 0, stream>>>(tbuf, TA, ceW1 + 2*DIM*DIM, ceb1 + 2*DIM,
                                                         ceW2 + 2*DIM*DIM, ceb2 + 2*DIM, DIM, 0, DIM, 0);
    const ushort_* Z16 = TA;

    // ---- h_orig pooling ----
    pool_orig_kernel<<<NB, 64, 0, stream>>>(Z16, batch, out_horig);

    // ---- edge masks (all experts fused) ----
    em_proj4_kernel<<<dim3(GT, 2*NK), 256, 0, stream>>>(Z16, emW1, pt4, pb4);
    edge_mask16_kernel<<<GW, 256, 0, stream>>>(pt4, pb4, rowptr, csr_src, csr_eid,
                                               emb1, emW2, emb2, em_out, ewi);

    // ---- node & feature masks (all experts via grid.y) ----
    nm4_kernel<<<dim3(GT, NK), 256, 0, stream>>>(Z16, nm_out, nmW1, nmb1, nmW2, nmb2);
    mlpX_kernel<1,1,0,1><<<dim3(GT, NK), 256, 0, stream>>>(Z16, fm_out, fmW1, fmb1, fmW2, fmb2,
                                                           DIM, 0, NK*DIM, DIM);

    // ---- masked input (Region A becomes h4A; Z16/tbuf/hx16 dead) ----
    build_h04_kernel<<<(N_NODES*64+255)/256, 256, 0, stream>>>(x, nm_out, fm_out, h4A);

    // ---- classifier GIN, 4 experts fused: h4A -> h4B -> h4A -> h4B ----
    agg4_kernel<<<GW, 256, 0, stream>>>(h4A, t16, rowptr, csr_src, ewi, cleps + 0);
    mlpX_kernel<1,0,1,0><<<dim3(GT, NK), 256, 0, stream>>>(t16, h4B, clW1 + 0*DIM*DIM, clb1 + 0*DIM,
                                                           clW2 + 0*DIM*DIM, clb2 + 0*DIM,
                                                           NK*DIM, DIM, NK*DIM, DIM);
    agg4_kernel<<<GW, 256, 0, stream>>>(h4B, t16, rowptr, csr_src, ewi, cleps + 1);
    mlpX_kernel<1,0,1,0><<<dim3(GT, NK), 256, 0, stream>>>(t16, h4A, clW1 + 1*DIM*DIM, clb1 + 1*DIM,
                                                           clW2 + 1*DIM*DIM, clb2 + 1*DIM,
                                                           NK*DIM, DIM, NK*DIM, DIM);
    agg4_kernel<<<GW, 256, 0, stream>>>(h4A, t16, rowptr, csr_src, ewi, cleps + 2);
    mlpX_kernel<1,0,1,0><<<dim3(GT, NK), 256, 0, stream>>>(t16, h4B, clW1 + 2*DIM*DIM, clb1 + 2*DIM,
                                                           clW2 + 2*DIM*DIM, clb2 + 2*DIM,
                                                           NK*DIM, DIM, NK*DIM, DIM);

    // ---- pooling + classifier ----
    pool4_kernel<<<dim3(NB, NK), 64, 0, stream>>>(h4B, batch, clfW, clfb, out_logits, out_hst);
}

// Round 9
// 909.834 us; speedup vs baseline: 3.0726x; 1.0940x over previous
//
#include <hip/hip_runtime.h>
#include <math.h>

#define N_NODES 50000
#define N_EDGES 800000
#define DIM 64
#define NB 256
#define NK 4
#define NC 10
#define TPAD 68
#define SCAN_BLKS 196  // ceil(50000/256)

typedef unsigned int uint_;
typedef unsigned short ushort_;
typedef unsigned char uchar_;
typedef float f32x2_ __attribute__((ext_vector_type(2)));

__device__ __forceinline__ float sigmoidf_(float x){ return 1.f/(1.f+__expf(-x)); }
__device__ __forceinline__ float bf2f(ushort_ v){ return __uint_as_float(((uint_)v)<<16); }
__device__ __forceinline__ float bflo(uint_ u){ return __uint_as_float(u<<16); }
__device__ __forceinline__ float bfhi(uint_ u){ return __uint_as_float(u & 0xFFFF0000u); }
__device__ __forceinline__ ushort_ f2bf(float f){
    uint_ u = __float_as_uint(f);
    u = (u + 0x7FFFu + ((u>>16)&1u)) >> 16;
    return (ushort_)u;
}
// fp8 e4m3 (OCP on gfx950) HW conversions
__device__ __forceinline__ f32x2_ fp8lo(uint_ u){ return __builtin_amdgcn_cvt_pk_f32_fp8(u, false); }
__device__ __forceinline__ f32x2_ fp8hi(uint_ u){ return __builtin_amdgcn_cvt_pk_f32_fp8(u, true); }
__device__ __forceinline__ uint_ pack_fp8x4(float a, float b, float c, float d){
    uint_ u = __builtin_amdgcn_cvt_pk_fp8_f32(a, b, 0, false);
    u = __builtin_amdgcn_cvt_pk_fp8_f32(c, d, u, true);
    return u;
}

// ---------------- CSR build ----------------
__global__ void deg_hist_kernel(const int* __restrict__ ei, int* __restrict__ deg){
    int e = blockIdx.x*256 + threadIdx.x;
    if (e < N_EDGES) atomicAdd(&deg[ei[N_EDGES + e]], 1);
}

__global__ __launch_bounds__(256)
void scan_p1(const int* __restrict__ deg, int* __restrict__ rowptr, int* __restrict__ bsum){
    __shared__ int s[256];
    int tid = threadIdx.x;
    int i = blockIdx.x*256 + tid;
    int v = (i < N_NODES) ? deg[i] : 0;
    s[tid] = v;
    __syncthreads();
    for (int off = 1; off < 256; off <<= 1){
        int t = (tid >= off) ? s[tid - off] : 0;
        __syncthreads();
        s[tid] += t;
        __syncthreads();
    }
    if (i < N_NODES) rowptr[i] = s[tid] - v;
    if (tid == 255) bsum[blockIdx.x] = s[255];
}

__global__ __launch_bounds__(256)
void scan_p2(const int* __restrict__ bsum, int* __restrict__ boff){
    __shared__ int s[256];
    int tid = threadIdx.x;
    int v = (tid < SCAN_BLKS) ? bsum[tid] : 0;
    s[tid] = v;
    __syncthreads();
    for (int off = 1; off < 256; off <<= 1){
        int t = (tid >= off) ? s[tid - off] : 0;
        __syncthreads();
        s[tid] += t;
        __syncthreads();
    }
    boff[tid] = s[tid] - v;
}

__global__ __launch_bounds__(256)
void scan_p3(int* __restrict__ rowptr, const int* __restrict__ boff, int* __restrict__ cursor){
    int i = blockIdx.x*256 + threadIdx.x;
    if (i < N_NODES){
        int r = rowptr[i] + boff[blockIdx.x];
        rowptr[i] = r;
        cursor[i] = r;
    }
    if (i == 0) rowptr[N_NODES] = N_EDGES;
}

__global__ void csr_fill_kernel(const int* __restrict__ ei, int* __restrict__ cursor,
                                int* __restrict__ csr_src, int* __restrict__ csr_eid){
    int e = blockIdx.x*256 + threadIdx.x;
    if (e < N_EDGES){
        int d = ei[N_EDGES + e];
        int pos = atomicAdd(&cursor[d], 1);
        csr_src[pos] = ei[e];
        csr_eid[pos] = e;
    }
}

// ---------------- f32 -> bf16 copy ----------------
__global__ void tobf16_kernel(const float* __restrict__ x, ushort_* __restrict__ o){
    int i = blockIdx.x*256 + threadIdx.x;
    if (i < N_NODES*DIM/4){
        float4 v = *(const float4*)&x[(size_t)i*4];
        ushort4 o4;
        o4.x = f2bf(v.x); o4.y = f2bf(v.y); o4.z = f2bf(v.z); o4.w = f2bf(v.w);
        *(ushort4*)&o[(size_t)i*4] = o4;
    }
}

// ---------------- CE aggregation: 2 feats/lane, 2 edges per half-wave, no ew ----------------
__global__ __launch_bounds__(256)
void agg_ce_kernel(const ushort_* __restrict__ hin, float* __restrict__ outt,
                   const int* __restrict__ rowptr, const int* __restrict__ csr_src,
                   const float* __restrict__ eps_p)
{
    const int n = blockIdx.x*4 + (threadIdx.x >> 6);
    if (n >= N_NODES) return;
    const int lane = threadIdx.x & 63;
    const int f2 = lane & 31;   // feature pair
    const int p  = lane >> 5;   // edge-group parity
    float a0 = 0.f, a1 = 0.f;
    int idx = rowptr[n];
    const int end = rowptr[n+1];
    for (; idx + 4 <= end; idx += 4){
        int e0 = idx + p*2, e1 = e0 + 1;
        int s0 = csr_src[e0], s1 = csr_src[e1];
        uint_ g0 = *(const uint_*)&hin[(size_t)s0*DIM + f2*2];
        uint_ g1 = *(const uint_*)&hin[(size_t)s1*DIM + f2*2];
        a0 += bflo(g0) + bflo(g1);
        a1 += bfhi(g0) + bfhi(g1);
    }
    for (; idx < end; idx += 2){
        int e = idx + p;
        bool v = e < end;
        int s = v ? csr_src[e] : 0;
        uint_ g = v ? *(const uint_*)&hin[(size_t)s*DIM + f2*2] : 0u;
        a0 += bflo(g);
        a1 += bfhi(g);
    }
    a0 += __shfl_xor(a0, 32);
    a1 += __shfl_xor(a1, 32);
    const float epv = 1.0f + *eps_p;
    uint_ hs = *(const uint_*)&hin[(size_t)n*DIM + f2*2];
    a0 = fmaf(epv, bflo(hs), a0);
    a1 = fmaf(epv, bfhi(hs), a1);
    if (p == 0){
        *(float2*)&outt[(size_t)n*DIM + f2*2] = make_float2(a0, a1);
    }
}

// ---------------- fused 4-expert CL aggregation, fp8 tables ----------------
// h4: fp8 [n][k*64+f], row = 256B = 64 uints; lane reads 1 uint (4 vals). ewi: [i*4+k] bf16.
__global__ __launch_bounds__(256)
void agg4_kernel(const uint_* __restrict__ h4, ushort_* __restrict__ out4,
                 const int* __restrict__ rowptr, const int* __restrict__ csr_src,
                 const ushort_* __restrict__ ewi, const float* __restrict__ eps_p)
{
    const int n = blockIdx.x*4 + (threadIdx.x >> 6);
    if (n >= N_NODES) return;
    const int lane = threadIdx.x & 63;
    const int k = lane >> 4;
    const float epv = 1.0f + *eps_p;
    uint_ self = h4[(size_t)n*64 + lane];
    f32x2_ sl = fp8lo(self), sh = fp8hi(self);
    float c0 = epv*sl.x, c1 = epv*sl.y, c2 = epv*sh.x, c3 = epv*sh.y;
    int idx = rowptr[n];
    const int end = rowptr[n+1];
    for (; idx + 4 <= end; idx += 4){
        int s0 = csr_src[idx+0], s1 = csr_src[idx+1];
        int s2 = csr_src[idx+2], s3 = csr_src[idx+3];
        uint_ g0 = h4[(size_t)s0*64 + lane];
        uint_ g1 = h4[(size_t)s1*64 + lane];
        uint_ g2 = h4[(size_t)s2*64 + lane];
        uint_ g3 = h4[(size_t)s3*64 + lane];
        float w0 = bf2f(ewi[(size_t)(idx+0)*NK + k]);
        float w1 = bf2f(ewi[(size_t)(idx+1)*NK + k]);
        float w2 = bf2f(ewi[(size_t)(idx+2)*NK + k]);
        float w3 = bf2f(ewi[(size_t)(idx+3)*NK + k]);
        f32x2_ l0 = fp8lo(g0), h0v = fp8hi(g0);
        f32x2_ l1 = fp8lo(g1), h1v = fp8hi(g1);
        f32x2_ l2 = fp8lo(g2), h2v = fp8hi(g2);
        f32x2_ l3 = fp8lo(g3), h3v = fp8hi(g3);
        c0 = fmaf(w0, l0.x, c0); c1 = fmaf(w0, l0.y, c1);
        c2 = fmaf(w0, h0v.x, c2); c3 = fmaf(w0, h0v.y, c3);
        c0 = fmaf(w1, l1.x, c0); c1 = fmaf(w1, l1.y, c1);
        c2 = fmaf(w1, h1v.x, c2); c3 = fmaf(w1, h1v.y, c3);
        c0 = fmaf(w2, l2.x, c0); c1 = fmaf(w2, l2.y, c1);
        c2 = fmaf(w2, h2v.x, c2); c3 = fmaf(w2, h2v.y, c3);
        c0 = fmaf(w3, l3.x, c0); c1 = fmaf(w3, l3.y, c1);
        c2 = fmaf(w3, h3v.x, c2); c3 = fmaf(w3, h3v.y, c3);
    }
    for (; idx < end; ++idx){
        int s = csr_src[idx];
        uint_ g = h4[(size_t)s*64 + lane];
        float w = bf2f(ewi[(size_t)idx*NK + k]);
        f32x2_ l = fp8lo(g), h = fp8hi(g);
        c0 = fmaf(w, l.x, c0); c1 = fmaf(w, l.y, c1);
        c2 = fmaf(w, h.x, c2); c3 = fmaf(w, h.y, c3);
    }
    ushort4 o;
    o.x = f2bf(c0); o.y = f2bf(c1); o.z = f2bf(c2); o.w = f2bf(c3);
    *(ushort4*)&out4[(size_t)n*(NK*DIM) + lane*4] = o;
}

// ---------------- LDS staging helpers (256 threads) ----------------
__device__ __forceinline__ void load_tileT_f32s(const float* __restrict__ in, float As[DIM][TPAD],
                                                int m0, int tid, int istride, int ibase){
    int r = tid >> 2, cq = (tid & 3) * 16;
    bool valid = (m0 + r) < N_NODES;
#pragma unroll
    for (int i = 0; i < 4; i++){
        float4 v = valid ? *(const float4*)&in[(size_t)(m0 + r)*istride + ibase + cq + 4*i]
                         : make_float4(0.f, 0.f, 0.f, 0.f);
        As[cq + 4*i + 0][r] = v.x;
        As[cq + 4*i + 1][r] = v.y;
        As[cq + 4*i + 2][r] = v.z;
        As[cq + 4*i + 3][r] = v.w;
    }
}

__device__ __forceinline__ void load_tileT_b16s(const ushort_* __restrict__ in, float As[DIM][TPAD],
                                                int m0, int tid, int istride, int ibase){
    int r = tid >> 2, cq = (tid & 3) * 16;
    bool valid = (m0 + r) < N_NODES;
    uint_ us[8] = {0,0,0,0,0,0,0,0};
    if (valid){
        const uint_* p = (const uint_*)&in[(size_t)(m0 + r)*istride + ibase + cq];
        uint4 a = *(const uint4*)p;
        uint4 b = *(const uint4*)(p + 4);
        us[0]=a.x; us[1]=a.y; us[2]=a.z; us[3]=a.w;
        us[4]=b.x; us[5]=b.y; us[6]=b.z; us[7]=b.w;
    }
#pragma unroll
    for (int w = 0; w < 8; w++){
        As[cq + 2*w + 0][r] = bflo(us[w]);
        As[cq + 2*w + 1][r] = bfhi(us[w]);
    }
}

__device__ __forceinline__ void load_w(const float* __restrict__ W, float Ws[DIM][TPAD], int tid){
    int kr = tid >> 2, cq = (tid & 3) * 16;
#pragma unroll
    for (int i = 0; i < 4; i++){
        *(float4*)&Ws[kr][cq + 4*i] = *(const float4*)&W[(size_t)kr*DIM + cq + 4*i];
    }
}

// ---------------- flexible fused 2-layer MLP over a 64-node tile ----------------
// grid.y = k. IN16: bf16 input. ACT2: 0=relu 1=sigmoid. OUTMODE: 0=f32 1=bf16 2=fp8.
// PERK_W: weights indexed by k. strides in elements; ibase=k*ibase_k, obase=k*obase_k.
template<int IN16, int ACT2, int OUTMODE, int PERK_W>
__global__ __launch_bounds__(256)
void mlpX_kernel(const void* __restrict__ inp, void* __restrict__ outp,
                 const float* __restrict__ W1, const float* __restrict__ b1,
                 const float* __restrict__ W2, const float* __restrict__ b2,
                 int istride, int ibase_k, int ostride, int obase_k)
{
    __shared__ __align__(16) float As[DIM][TPAD];
    __shared__ __align__(16) float Ws[DIM][TPAD];
    __shared__ __align__(16) float Ts[DIM][TPAD];
    const int tid = threadIdx.x;
    const int tx = tid & 15, ty = tid >> 4;
    const int m0 = blockIdx.x * 64;
    const int k = blockIdx.y;
    if (PERK_W){
        W1 += (size_t)k*DIM*DIM; b1 += (size_t)k*DIM;
        W2 += (size_t)k*DIM*DIM; b2 += (size_t)k*DIM;
    }
    const int ibase = k * ibase_k;
    const size_t obase = (size_t)k * obase_k;

    if (IN16) load_tileT_b16s((const ushort_*)inp, As, m0, tid, istride, ibase);
    else      load_tileT_f32s((const float*)inp, As, m0, tid, istride, ibase);
    load_w(W1, Ws, tid);
    __syncthreads();

    float acc[4][4];
    {
        float4 b1v = *(const float4*)&b1[tx*4];
        float bv[4] = {b1v.x, b1v.y, b1v.z, b1v.w};
#pragma unroll
        for (int i = 0; i < 4; i++)
#pragma unroll
            for (int j = 0; j < 4; j++) acc[i][j] = bv[j];
    }
#pragma unroll 8
    for (int kk = 0; kk < DIM; kk++){
        float4 a = *(const float4*)&As[kk][ty*4];
        float4 w = *(const float4*)&Ws[kk][tx*4];
        float av[4] = {a.x, a.y, a.z, a.w};
        float wv[4] = {w.x, w.y, w.z, w.w};
#pragma unroll
        for (int i = 0; i < 4; i++)
#pragma unroll
            for (int j = 0; j < 4; j++) acc[i][j] = fmaf(av[i], wv[j], acc[i][j]);
    }
#pragma unroll
    for (int j = 0; j < 4; j++){
        float4 v = make_float4(fmaxf(acc[0][j],0.f), fmaxf(acc[1][j],0.f),
                               fmaxf(acc[2][j],0.f), fmaxf(acc[3][j],0.f));
        *(float4*)&Ts[tx*4 + j][ty*4] = v;
    }
    __syncthreads();
    load_w(W2, Ws, tid);
    __syncthreads();

    float acc2[4][4];
    {
        float4 b2v = *(const float4*)&b2[tx*4];
        float bv[4] = {b2v.x, b2v.y, b2v.z, b2v.w};
#pragma unroll
        for (int i = 0; i < 4; i++)
#pragma unroll
            for (int j = 0; j < 4; j++) acc2[i][j] = bv[j];
    }
#pragma unroll 8
    for (int kk = 0; kk < DIM; kk++){
        float4 a = *(const float4*)&Ts[kk][ty*4];
        float4 w = *(const float4*)&Ws[kk][tx*4];
        float av[4] = {a.x, a.y, a.z, a.w};
        float wv[4] = {w.x, w.y, w.z, w.w};
#pragma unroll
        for (int i = 0; i < 4; i++)
#pragma unroll
            for (int j = 0; j < 4; j++) acc2[i][j] = fmaf(av[i], wv[j], acc2[i][j]);
    }
#pragma unroll
    for (int i = 0; i < 4; i++){
        int m = m0 + ty*4 + i;
        if (m < N_NODES){
            float v0, v1, v2, v3;
            if (ACT2 == 0){
                v0 = fmaxf(acc2[i][0],0.f); v1 = fmaxf(acc2[i][1],0.f);
                v2 = fmaxf(acc2[i][2],0.f); v3 = fmaxf(acc2[i][3],0.f);
            } else {
                v0 = sigmoidf_(acc2[i][0]); v1 = sigmoidf_(acc2[i][1]);
                v2 = sigmoidf_(acc2[i][2]); v3 = sigmoidf_(acc2[i][3]);
            }
            if (OUTMODE == 1){
                ushort4 o;
                o.x = f2bf(v0); o.y = f2bf(v1); o.z = f2bf(v2); o.w = f2bf(v3);
                *(ushort4*)&((ushort_*)outp)[obase + (size_t)m*ostride + tx*4] = o;
            } else if (OUTMODE == 2){
                uint_ u = pack_fp8x4(v0, v1, v2, v3);
                ((uint_*)outp)[(obase >> 2) + (size_t)m*(ostride >> 2) + tx] = u;
            } else {
                *(float4*)&((float*)outp)[obase + (size_t)m*ostride + tx*4] =
                    make_float4(v0, v1, v2, v3);
            }
        }
    }
}

// ---------------- node-mask (all experts via grid.y) ----------------
__global__ __launch_bounds__(256)
void nm4_kernel(const ushort_* __restrict__ Z16, float* __restrict__ nm_out,
                const float* __restrict__ nmW1, const float* __restrict__ nmb1,
                const float* __restrict__ nmW2, const float* __restrict__ nmb2)
{
    __shared__ __align__(16) float As[DIM][TPAD];
    __shared__ __align__(16) float Ws[DIM][TPAD];
    __shared__ __align__(16) float Ts[DIM][TPAD];
    __shared__ float w2s[DIM];
    __shared__ float red[4][DIM];
    const int tid = threadIdx.x;
    const int tx = tid & 15, ty = tid >> 4;
    const int m0 = blockIdx.x * 64;
    const int k = blockIdx.y;
    const float* W1 = nmW1 + (size_t)k*DIM*DIM;
    const float* b1 = nmb1 + (size_t)k*DIM;
    const float* w2 = nmW2 + (size_t)k*DIM;

    load_tileT_b16s(Z16, As, m0, tid, DIM, 0);
    load_w(W1, Ws, tid);
    if (tid < DIM) w2s[tid] = w2[tid];
    __syncthreads();

    float acc[4][4];
    {
        float4 b1v = *(const float4*)&b1[tx*4];
        float bv[4] = {b1v.x, b1v.y, b1v.z, b1v.w};
#pragma unroll
        for (int i = 0; i < 4; i++)
#pragma unroll
            for (int j = 0; j < 4; j++) acc[i][j] = bv[j];
    }
#pragma unroll 8
    for (int kk = 0; kk < DIM; kk++){
        float4 a = *(const float4*)&As[kk][ty*4];
        float4 w = *(const float4*)&Ws[kk][tx*4];
        float av[4] = {a.x, a.y, a.z, a.w};
        float wv[4] = {w.x, w.y, w.z, w.w};
#pragma unroll
        for (int i = 0; i < 4; i++)
#pragma unroll
            for (int j = 0; j < 4; j++) acc[i][j] = fmaf(av[i], wv[j], acc[i][j]);
    }
#pragma unroll
    for (int j = 0; j < 4; j++){
        float4 v = make_float4(fmaxf(acc[0][j],0.f), fmaxf(acc[1][j],0.f),
                               fmaxf(acc[2][j],0.f), fmaxf(acc[3][j],0.f));
        *(float4*)&Ts[tx*4 + j][ty*4] = v;
    }
    __syncthreads();
    {
        int m = tid & 63, q = tid >> 6;
        float p = 0.f;
#pragma unroll
        for (int kk = 0; kk < 16; kk++) p = fmaf(Ts[q*16 + kk][m], w2s[q*16 + kk], p);
        red[q][m] = p;
    }
    __syncthreads();
    if (tid < DIM){
        int m = m0 + tid;
        if (m < N_NODES){
            float sm = red[0][tid] + red[1][tid] + red[2][tid] + red[3][tid] + nmb2[k];
            nm_out[(size_t)m*NK + k] = sigmoidf_(sm);
        }
    }
}

// ---------------- edge-mask projections for ALL experts (fp8 out): grid (tiles, 8) ----------------
__global__ __launch_bounds__(256)
void em_proj4_kernel(const ushort_* __restrict__ Z16, const float* __restrict__ emW1,
                     uint_* __restrict__ pt4, uint_* __restrict__ pb4)
{
    __shared__ __align__(16) float As[DIM][TPAD];
    __shared__ __align__(16) float Ws[DIM][TPAD];
    const int s = blockIdx.y;
    const int k = s >> 1, side = s & 1;
    const float* W = emW1 + ((size_t)k*2 + side)*DIM*DIM;
    uint_* outp = side ? pb4 : pt4;
    const int tid = threadIdx.x;
    const int tx = tid & 15, ty = tid >> 4;
    const int m0 = blockIdx.x * 64;

    load_tileT_b16s(Z16, As, m0, tid, DIM, 0);
    load_w(W, Ws, tid);
    __syncthreads();

    float acc[4][4] = {};
#pragma unroll 8
    for (int kk = 0; kk < DIM; kk++){
        float4 a = *(const float4*)&As[kk][ty*4];
        float4 w = *(const float4*)&Ws[kk][tx*4];
        float av[4] = {a.x, a.y, a.z, a.w};
        float wv[4] = {w.x, w.y, w.z, w.w};
#pragma unroll
        for (int i = 0; i < 4; i++)
#pragma unroll
            for (int j = 0; j < 4; j++) acc[i][j] = fmaf(av[i], wv[j], acc[i][j]);
    }
#pragma unroll
    for (int i = 0; i < 4; i++){
        int m = m0 + ty*4 + i;
        if (m < N_NODES){
            // fp8 row: 64 uints; slice k -> 16 uints; tx -> one uint (4 vals)
            outp[(size_t)m*64 + k*16 + tx] = pack_fp8x4(acc[i][0], acc[i][1], acc[i][2], acc[i][3]);
        }
    }
}

// ---------------- edge mask, all 4 experts, wave-per-node over CSR (fp8 tables) ----------------
__global__ __launch_bounds__(256)
void edge_mask16_kernel(const uint_* __restrict__ pt4, const uint_* __restrict__ pb4,
                        const int* __restrict__ rowptr, const int* __restrict__ csr_src,
                        const int* __restrict__ csr_eid,
                        const float* __restrict__ emb1, const float* __restrict__ emW2,
                        const float* __restrict__ emb2,
                        float* __restrict__ em_out, ushort_* __restrict__ ewi)
{
    const int n = blockIdx.x*4 + (threadIdx.x >> 6);
    if (n >= N_NODES) return;
    const int lane = threadIdx.x & 63;
    const int k = lane >> 4, fq = lane & 15;
    const float4 w2v = *(const float4*)&emW2[k*DIM + fq*4];
    const float4 b1v = *(const float4*)&emb1[k*DIM + fq*4];
    const float b2 = emb2[k];
    uint_ pbu = pb4[(size_t)n*64 + k*16 + fq];
    f32x2_ plo = fp8lo(pbu), phi = fp8hi(pbu);
    const float pre0 = plo.x + b1v.x;
    const float pre1 = plo.y + b1v.y;
    const float pre2 = phi.x + b1v.z;
    const float pre3 = phi.y + b1v.w;
    int i = rowptr[n];
    const int end = rowptr[n+1];
    for (; i + 2 <= end; i += 2){
        int s0 = csr_src[i], s1 = csr_src[i+1];
        uint_ a0 = pt4[(size_t)s0*64 + k*16 + fq];
        uint_ a1 = pt4[(size_t)s1*64 + k*16 + fq];
        f32x2_ a0l = fp8lo(a0), a0h = fp8hi(a0);
        f32x2_ a1l = fp8lo(a1), a1h = fp8hi(a1);
        float p0 = fmaxf(a0l.x + pre0, 0.f)*w2v.x + fmaxf(a0l.y + pre1, 0.f)*w2v.y
                 + fmaxf(a0h.x + pre2, 0.f)*w2v.z + fmaxf(a0h.y + pre3, 0.f)*w2v.w;
        float p1 = fmaxf(a1l.x + pre0, 0.f)*w2v.x + fmaxf(a1l.y + pre1, 0.f)*w2v.y
                 + fmaxf(a1h.x + pre2, 0.f)*w2v.z + fmaxf(a1h.y + pre3, 0.f)*w2v.w;
        p0 += __shfl_xor(p0, 1, 16); p1 += __shfl_xor(p1, 1, 16);
        p0 += __shfl_xor(p0, 2, 16); p1 += __shfl_xor(p1, 2, 16);
        p0 += __shfl_xor(p0, 4, 16); p1 += __shfl_xor(p1, 4, 16);
        p0 += __shfl_xor(p0, 8, 16); p1 += __shfl_xor(p1, 8, 16);
        if (fq == 0){
            float m0v = sigmoidf_(p0 + b2);
            float m1v = sigmoidf_(p1 + b2);
            em_out[(size_t)csr_eid[i]*NK + k]   = m0v;
            em_out[(size_t)csr_eid[i+1]*NK + k] = m1v;
            ewi[(size_t)i*NK + k]     = f2bf(m0v);
            ewi[(size_t)(i+1)*NK + k] = f2bf(m1v);
        }
    }
    for (; i < end; ++i){
        int s0 = csr_src[i];
        uint_ a0 = pt4[(size_t)s0*64 + k*16 + fq];
        f32x2_ a0l = fp8lo(a0), a0h = fp8hi(a0);
        float p0 = fmaxf(a0l.x + pre0, 0.f)*w2v.x + fmaxf(a0l.y + pre1, 0.f)*w2v.y
                 + fmaxf(a0h.x + pre2, 0.f)*w2v.z + fmaxf(a0h.y + pre3, 0.f)*w2v.w;
        p0 += __shfl_xor(p0, 1, 16);
        p0 += __shfl_xor(p0, 2, 16);
        p0 += __shfl_xor(p0, 4, 16);
        p0 += __shfl_xor(p0, 8, 16);
        if (fq == 0){
            float m0v = sigmoidf_(p0 + b2);
            em_out[(size_t)csr_eid[i]*NK + k] = m0v;
            ewi[(size_t)i*NK + k] = f2bf(m0v);
        }
    }
}

// ---------------- masked_x for all experts -> interleaved fp8 h4 ----------------
__global__ void build_h04_kernel(const float* __restrict__ x, const float* __restrict__ nm_out,
                                 const float* __restrict__ fm_out, uint_* __restrict__ h4)
{
    int t = blockIdx.x*256 + threadIdx.x;
    if (t < N_NODES*64){
        int n = t >> 6;
        int q = t & 63;           // q = k*16 + c4
        int k = q >> 4, c = (q & 15) * 4;
        float nm = nm_out[(size_t)n*NK + k];
        float4 xv = *(const float4*)&x[(size_t)n*DIM + c];
        float4 fv = *(const float4*)&fm_out[((size_t)n*NK + k)*DIM + c];
        h4[(size_t)n*64 + q] = pack_fp8x4(xv.x*nm*fv.x, xv.y*nm*fv.y,
                                          xv.z*nm*fv.z, xv.w*nm*fv.w);
    }
}

// ---------------- pooling ----------------
__device__ __forceinline__ int lower_bound_(const int* a, int n, int v){
    int lo = 0, hi = n;
    while (lo < hi){ int m = (lo + hi) >> 1; if (a[m] < v) lo = m + 1; else hi = m; }
    return lo;
}

__global__ __launch_bounds__(64)
void pool_orig_kernel(const ushort_* __restrict__ h, const int* __restrict__ batch, float* __restrict__ out){
    int b = blockIdx.x, lane = threadIdx.x;
    int lo = lower_bound_(batch, N_NODES, b);
    int hi = lower_bound_(batch, N_NODES, b+1);
    float s = 0.f;
    int n = lo;
    for (; n + 4 <= hi; n += 4){
        s += bf2f(h[(size_t)n*DIM + lane]) + bf2f(h[(size_t)(n+1)*DIM + lane])
           + bf2f(h[(size_t)(n+2)*DIM + lane]) + bf2f(h[(size_t)(n+3)*DIM + lane]);
    }
    for (; n < hi; ++n) s += bf2f(h[(size_t)n*DIM + lane]);
    out[(size_t)b*DIM + lane] = s / fmaxf((float)(hi - lo), 1.f);
}

__global__ __launch_bounds__(64)
void pool4_kernel(const uint_* __restrict__ h4, const int* __restrict__ batch,
                  const float* __restrict__ clfW, const float* __restrict__ clfb,
                  float* __restrict__ out_logits, float* __restrict__ out_hst)
{
    __shared__ float ms[DIM];
    int b = blockIdx.x, k = blockIdx.y, lane = threadIdx.x;
    int lo = lower_bound_(batch, N_NODES, b);
    int hi = lower_bound_(batch, N_NODES, b+1);
    const uchar_* h = (const uchar_*)h4 + (size_t)k*DIM + lane;  // fp8 row = 256B
    float s = 0.f;
    int n = lo;
    for (; n + 4 <= hi; n += 4){
        s += __builtin_amdgcn_cvt_f32_fp8((uint_)h[(size_t)n*256], 0)
           + __builtin_amdgcn_cvt_f32_fp8((uint_)h[(size_t)(n+1)*256], 0)
           + __builtin_amdgcn_cvt_f32_fp8((uint_)h[(size_t)(n+2)*256], 0)
           + __builtin_amdgcn_cvt_f32_fp8((uint_)h[(size_t)(n+3)*256], 0);
    }
    for (; n < hi; ++n) s += __builtin_amdgcn_cvt_f32_fp8((uint_)h[(size_t)n*256], 0);
    float m = s / fmaxf((float)(hi - lo), 1.f);
    out_hst[((size_t)b*NK + k)*DIM + lane] = m;
    ms[lane] = m;
    __syncthreads();
    if (lane < NC){
        float a = clfb[(size_t)k*NC + lane];
        const float* W = clfW + (size_t)k*DIM*NC;
#pragma unroll
        for (int j = 0; j < DIM; j++) a = fmaf(ms[j], W[j*NC + lane], a);
        out_logits[((size_t)b*NK + k)*NC + lane] = a;
    }
}

// ---------------- launch ----------------
extern "C" void kernel_launch(void* const* d_in, const int* in_sizes, int n_in,
                              void* d_out, int out_size, void* d_ws, size_t ws_size,
                              hipStream_t stream)
{
    const float* x     = (const float*)d_in[0];
    const int*   ei    = (const int*)  d_in[1];
    const int*   batch = (const int*)  d_in[2];
    const float* ceW1 = (const float*)d_in[3];
    const float* ceb1 = (const float*)d_in[4];
    const float* ceW2 = (const float*)d_in[5];
    const float* ceb2 = (const float*)d_in[6];
    const float* ceeps= (const float*)d_in[7];
    const float* clW1 = (const float*)d_in[8];
    const float* clb1 = (const float*)d_in[9];
    const float* clW2 = (const float*)d_in[10];
    const float* clb2 = (const float*)d_in[11];
    const float* cleps= (const float*)d_in[12];
    const float* nmW1 = (const float*)d_in[13];
    const float* nmb1 = (const float*)d_in[14];
    const float* nmW2 = (const float*)d_in[15];
    const float* nmb2 = (const float*)d_in[16];
    const float* emW1 = (const float*)d_in[17];
    const float* emb1 = (const float*)d_in[18];
    const float* emW2 = (const float*)d_in[19];
    const float* emb2 = (const float*)d_in[20];
    const float* fmW1 = (const float*)d_in[21];
    const float* fmb1 = (const float*)d_in[22];
    const float* fmW2 = (const float*)d_in[23];
    const float* fmb2 = (const float*)d_in[24];
    const float* clfW = (const float*)d_in[25];
    const float* clfb = (const float*)d_in[26];

    // output layout (f32, flat, return order)
    float* out        = (float*)d_out;
    float* out_logits = out;                       // [B,K,C]
    float* out_hst    = out + 10240;               // [B,K,H]
    float* out_horig  = out + 75776;               // [B,H]
    float* nm_out     = out + 92160;               // [N,K]
    float* em_out     = out + 292160;              // [E,K]
    float* fm_out     = out + 3492160;             // [N,K,F]

    // workspace layout (~85MB)
    int* rowptr  = (int*)d_ws;                     // N+1
    int* cursor  = rowptr + (N_NODES + 1);         // N
    int* deg     = cursor + N_NODES;               // N
    int* csr_src = deg + N_NODES;                  // E
    int* csr_eid = csr_src + N_EDGES;              // E
    int* bsum    = csr_eid + N_EDGES;              // 256
    int* boff    = bsum + 256;                     // 256
    size_t int_count = (size_t)(N_NODES+1) + N_NODES + N_NODES + N_EDGES + N_EDGES + 512;
    int_count = (int_count + 3) & ~(size_t)3;
    const size_t ND = (size_t)N_NODES*DIM;
    // Region A (25.6MB): CE-phase {tbuf f32 (12.8) | hx16 (6.4) | TA (6.4)}; CL-phase h4A (fp8 12.8, overlays tbuf)
    float*   tbuf = (float*)(((int*)d_ws) + int_count);
    ushort_* hx16 = (ushort_*)(tbuf + ND);
    ushort_* TA   = hx16 + ND;                     // Z16 after CE
    uint_*   h4A  = (uint_*)tbuf;                  // N*64 uints (fp8), fits in tbuf's 12.8MB
    ushort_* TB   = TA + ND;                       // N*64 bf16 (6.4)
    uint_*   pt4  = (uint_*)(TB + ND);             // N*64 uints fp8 (12.8)
    uint_*   pb4  = pt4 + (size_t)N_NODES*64;      // N*64 uints fp8 (12.8)
    ushort_* t16  = (ushort_*)pt4;                 // N*256 bf16 (25.6) overlays pt4+pb4 (CL phase)
    ushort_* ewi  = (ushort_*)(pb4 + (size_t)N_NODES*64);  // E*4 bf16 (6.4)
    uint_*   h4B  = (uint_*)(ewi + (size_t)N_EDGES*NK);    // N*64 uints fp8 (12.8)

    const int GT = (N_NODES + 63) / 64;     // 782 tiles
    const int GW = (N_NODES + 3) / 4;       // wave-per-node blocks

    // ---- CSR build ----
    hipMemsetAsync(deg, 0, N_NODES*sizeof(int), stream);
    deg_hist_kernel<<<(N_EDGES+255)/256, 256, 0, stream>>>(ei, deg);
    scan_p1<<<SCAN_BLKS, 256, 0, stream>>>(deg, rowptr, bsum);
    scan_p2<<<1, 256, 0, stream>>>(bsum, boff);
    scan_p3<<<SCAN_BLKS, 256, 0, stream>>>(rowptr, boff, cursor);
    csr_fill_kernel<<<(N_EDGES+255)/256, 256, 0, stream>>>(ei, cursor, csr_src, csr_eid);

    // ---- x -> bf16 ----
    tobf16_kernel<<<(N_NODES*DIM/4+255)/256, 256, 0, stream>>>(x, hx16);

    // ---- causal encoder GIN (3 layers): hx16 -> TA -> TB -> TA (Z16 = TA) ----
    agg_ce_kernel<<<GW, 256, 0, stream>>>(hx16, tbuf, rowptr, csr_src, ceeps + 0);
    mlpX_kernel<0,0,1,0><<<dim3(GT,1), 256, 0, stream>>>(tbuf, TA, ceW1 + 0*DIM*DIM, ceb1 + 0*DIM,
                                                         ceW2 + 0*DIM*DIM, ceb2 + 0*DIM, DIM, 0, DIM, 0);
    agg_ce_kernel<<<GW, 256, 0, stream>>>(TA, tbuf, rowptr, csr_src, ceeps + 1);
    mlpX_kernel<0,0,1,0><<<dim3(GT,1), 256, 0, stream>>>(tbuf, TB, ceW1 + 1*DIM*DIM, ceb1 + 1*DIM,
                                                         ceW2 + 1*DIM*DIM, ceb2 + 1*DIM, DIM, 0, DIM, 0);
    agg_ce_kernel<<<GW, 256, 0, stream>>>(TB, tbuf, rowptr, csr_src, ceeps + 2);
    mlpX_kernel<0,0,1,0><<<dim3(GT,1), 256, 0, stream>>>(tbuf, TA, ceW1 + 2*DIM*DIM, ceb1 + 2*DIM,
                                                         ceW2 + 2*DIM*DIM, ceb2 + 2*DIM, DIM, 0, DIM, 0);
    const ushort_* Z16 = TA;

    // ---- h_orig pooling ----
    pool_orig_kernel<<<NB, 64, 0, stream>>>(Z16, batch, out_horig);

    // ---- edge masks (all experts fused, fp8 tables) ----
    em_proj4_kernel<<<dim3(GT, 2*NK), 256, 0, stream>>>(Z16, emW1, pt4, pb4);
    edge_mask16_kernel<<<GW, 256, 0, stream>>>(pt4, pb4, rowptr, csr_src, csr_eid,
                                               emb1, emW2, emb2, em_out, ewi);

    // ---- node & feature masks (all experts via grid.y) ----
    nm4_kernel<<<dim3(GT, NK), 256, 0, stream>>>(Z16, nm_out, nmW1, nmb1, nmW2, nmb2);
    mlpX_kernel<1,1,0,1><<<dim3(GT, NK), 256, 0, stream>>>(Z16, fm_out, fmW1, fmb1, fmW2, fmb2,
                                                           DIM, 0, NK*DIM, DIM);

    // ---- masked input (Region A becomes h4A; Z16 dead after this point) ----
    build_h04_kernel<<<(N_NODES*64+255)/256, 256, 0, stream>>>(x, nm_out, fm_out, h4A);

    // ---- classifier GIN, 4 experts fused, fp8 tables: h4A -> h4B -> h4A -> h4B ----
    agg4_kernel<<<GW, 256, 0, stream>>>(h4A, t16, rowptr, csr_src, ewi, cleps + 0);
    mlpX_kernel<1,0,2,0><<<dim3(GT, NK), 256, 0, stream>>>(t16, h4B, clW1 + 0*DIM*DIM, clb1 + 0*DIM,
                                                           clW2 + 0*DIM*DIM, clb2 + 0*DIM,
                                                           NK*DIM, DIM, NK*DIM, DIM);
    agg4_kernel<<<GW, 256, 0, stream>>>(h4B, t16, rowptr, csr_src, ewi, cleps + 1);
    mlpX_kernel<1,0,2,0><<<dim3(GT, NK), 256, 0, stream>>>(t16, h4A, clW1 + 1*DIM*DIM, clb1 + 1*DIM,
                                                           clW2 + 1*DIM*DIM, clb2 + 1*DIM,
                                                           NK*DIM, DIM, NK*DIM, DIM);
    agg4_kernel<<<GW, 256, 0, stream>>>(h4A, t16, rowptr, csr_src, ewi, cleps + 2);
    mlpX_kernel<1,0,2,0><<<dim3(GT, NK), 256, 0, stream>>>(t16, h4B, clW1 + 2*DIM*DIM, clb1 + 2*DIM,
                                                           clW2 + 2*DIM*DIM, clb2 + 2*DIM,
                                                           NK*DIM, DIM, NK*DIM, DIM);

    // ---- pooling + classifier ----
    pool4_kernel<<<dim3(NB, NK), 64, 0, stream>>>(h4B, batch, clfW, clfb, out_logits, out_hst);
}